// Round 1
// baseline (471.740 us; speedup 1.0000x reference)
//
#include <hip/hip_runtime.h>

// Shapes (fixed by the problem)
#define B_ 2
#define S_ 2048
#define D_ 1024
#define H_ 16
#define HS_ 64
#define HD_ 1024   // H_*HS_
#define SPLIT 8    // S-split for the K^T V reduction

// ---------------------------------------------------------------------------
// Kernel 1: K/V head projections.
// K[b,s,h*64+f] = sum_d x[b,s,d] * Wk[h,d,f]  (same for V with Wv)
// One block = one (b, h, 64-row s-tile); computes BOTH K and V tiles reusing
// the x LDS tile. grid = B*H*(S/64) = 1024 blocks, 256 threads.
// ---------------------------------------------------------------------------
__global__ __launch_bounds__(256) void kv_proj_kernel(
    const float* __restrict__ x, const float* __restrict__ Wk,
    const float* __restrict__ Wv, float* __restrict__ Kall,
    float* __restrict__ Vall) {
  const int blk = blockIdx.x;
  const int stile = blk & 31;        // S/64 = 32
  const int h = (blk >> 5) & 15;
  const int b = blk >> 9;
  const int s0 = stile * 64;
  const int tid = threadIdx.x;
  const int tx = tid & 15, ty = tid >> 4;

  // pad 68 keeps float4 LDS reads 16B-aligned (68 % 4 == 0)
  __shared__ float xs[32][68];   // [k][m], transposed on store
  __shared__ float wks[32][64];  // [k][n]
  __shared__ float wvs[32][64];

  float accK[4][4] = {};
  float accV[4][4] = {};

  for (int d0 = 0; d0 < D_; d0 += 32) {
#pragma unroll
    for (int i = 0; i < 8; ++i) {  // x tile 64x32, store transposed
      int idx = tid + i * 256;
      int r = idx >> 5, c = idx & 31;
      xs[c][r] = x[(size_t)(b * S_ + s0 + r) * D_ + d0 + c];
    }
#pragma unroll
    for (int i = 0; i < 8; ++i) {  // Wk/Wv tiles 32x64
      int idx = tid + i * 256;
      int r = idx >> 6, c = idx & 63;
      size_t g = (size_t)(h * D_ + d0 + r) * HS_ + c;
      wks[r][c] = Wk[g];
      wvs[r][c] = Wv[g];
    }
    __syncthreads();
#pragma unroll
    for (int kk = 0; kk < 32; ++kk) {
      const float4 a4 = *(const float4*)&xs[kk][ty * 4];
      const float4 bk4 = *(const float4*)&wks[kk][tx * 4];
      const float4 bv4 = *(const float4*)&wvs[kk][tx * 4];
      const float a[4] = {a4.x, a4.y, a4.z, a4.w};
      const float bk[4] = {bk4.x, bk4.y, bk4.z, bk4.w};
      const float bv[4] = {bv4.x, bv4.y, bv4.z, bv4.w};
#pragma unroll
      for (int i = 0; i < 4; ++i)
#pragma unroll
        for (int j = 0; j < 4; ++j) {
          accK[i][j] += a[i] * bk[j];
          accV[i][j] += a[i] * bv[j];
        }
    }
    __syncthreads();
  }
#pragma unroll
  for (int i = 0; i < 4; ++i) {
    size_t row = (size_t)(b * S_ + s0 + ty * 4 + i) * HD_ + h * HS_ + tx * 4;
    float4 k4 = {accK[i][0], accK[i][1], accK[i][2], accK[i][3]};
    float4 v4 = {accV[i][0], accV[i][1], accV[i][2], accV[i][3]};
    *(float4*)&Kall[row] = k4;
    *(float4*)&Vall[row] = v4;
  }
}

// ---------------------------------------------------------------------------
// Kernel 2: partial M = K^T V over an S-slice.
// Mpart[split, b, h, f, e] = sum_{s in slice} K[b,s,h*64+f] * V[b,s,h*64+e]
// grid = SPLIT*B*H = 256 blocks (so we use >32 CUs), 256 threads.
// ---------------------------------------------------------------------------
__global__ __launch_bounds__(256) void m_partial_kernel(
    const float* __restrict__ Kall, const float* __restrict__ Vall,
    float* __restrict__ Mpart) {
  const int blk = blockIdx.x;
  const int h = blk & 15;
  const int b = (blk >> 4) & 1;
  const int split = blk >> 5;
  const int tid = threadIdx.x;
  const int tx = tid & 15, ty = tid >> 4;
  __shared__ float Ks[64][68];
  __shared__ float Vs[64][68];
  float acc[4][4] = {};
  const int sBase = split * (S_ / SPLIT);
  for (int sc = 0; sc < S_ / SPLIT; sc += 64) {
#pragma unroll
    for (int i = 0; i < 16; ++i) {
      int idx = tid + i * 256;
      int r = idx >> 6, c = idx & 63;
      size_t g = (size_t)(b * S_ + sBase + sc + r) * HD_ + h * HS_ + c;
      Ks[r][c] = Kall[g];
      Vs[r][c] = Vall[g];
    }
    __syncthreads();
#pragma unroll
    for (int ss = 0; ss < 64; ++ss) {
      const float4 a4 = *(const float4*)&Ks[ss][ty * 4];
      const float4 b4 = *(const float4*)&Vs[ss][tx * 4];
      const float a[4] = {a4.x, a4.y, a4.z, a4.w};
      const float bb[4] = {b4.x, b4.y, b4.z, b4.w};
#pragma unroll
      for (int i = 0; i < 4; ++i)
#pragma unroll
        for (int j = 0; j < 4; ++j) acc[i][j] += a[i] * bb[j];
    }
    __syncthreads();
  }
  float* dst = Mpart + ((size_t)(split * B_ + b) * H_ + h) * HS_ * HS_;
#pragma unroll
  for (int i = 0; i < 4; ++i) {
    float4 o = {acc[i][0], acc[i][1], acc[i][2], acc[i][3]};
    *(float4*)&dst[(ty * 4 + i) * HS_ + tx * 4] = o;
  }
}

// ---------------------------------------------------------------------------
// Kernel 3: reduce the SPLIT partials, apply the 1/sqrt(HS)=0.125 scale.
// grid = B*H = 32 blocks, 256 threads.
// ---------------------------------------------------------------------------
__global__ __launch_bounds__(256) void m_reduce_kernel(
    const float* __restrict__ Mpart, float* __restrict__ M) {
  const int bh = blockIdx.x;
  const int tid = threadIdx.x;
  for (int idx = tid; idx < HS_ * HS_; idx += 256) {
    float s = 0.f;
#pragma unroll
    for (int p = 0; p < SPLIT; ++p)
      s += Mpart[((size_t)(p * B_ * H_) + bh) * (HS_ * HS_) + idx];
    M[(size_t)bh * (HS_ * HS_) + idx] = s * 0.125f;
  }
}

// ---------------------------------------------------------------------------
// Kernel 4: P[b, h*64+f, d] = sum_e M[b,h,f,e] * Wproj[h*64+e, d]
// (scale already folded into M). K=64, single LDS pass.
// grid = B*H*(D/64) = 512 blocks, 256 threads.
// ---------------------------------------------------------------------------
__global__ __launch_bounds__(256) void p_kernel(
    const float* __restrict__ M, const float* __restrict__ Wproj,
    float* __restrict__ P) {
  const int blk = blockIdx.x;
  const int dtile = blk & 15;
  const int h = (blk >> 4) & 15;
  const int b = blk >> 8;
  const int d0 = dtile * 64;
  const int tid = threadIdx.x;
  const int tx = tid & 15, ty = tid >> 4;
  __shared__ float Ms[64][68];  // [e][f], transposed on store
  __shared__ float Ws[64][68];  // [e][d]
  const size_t mbase = ((size_t)(b * H_ + h)) * HS_ * HS_;
#pragma unroll
  for (int i = 0; i < 16; ++i) {
    int idx = tid + i * 256;
    int f = idx >> 6, e = idx & 63;
    Ms[e][f] = M[mbase + idx];
    Ws[f][e] = Wproj[(size_t)(h * HS_ + f) * D_ + d0 + e];  // here f is row idx
  }
  __syncthreads();
  float acc[4][4] = {};
#pragma unroll
  for (int kk = 0; kk < 64; ++kk) {
    const float4 a4 = *(const float4*)&Ms[kk][ty * 4];
    const float4 b4 = *(const float4*)&Ws[kk][tx * 4];
    const float a[4] = {a4.x, a4.y, a4.z, a4.w};
    const float bb[4] = {b4.x, b4.y, b4.z, b4.w};
#pragma unroll
    for (int i = 0; i < 4; ++i)
#pragma unroll
      for (int j = 0; j < 4; ++j) acc[i][j] += a[i] * bb[j];
  }
#pragma unroll
  for (int i = 0; i < 4; ++i) {
    float4 o = {acc[i][0], acc[i][1], acc[i][2], acc[i][3]};
    *(float4*)&P[(size_t)(b * HD_ + h * HS_ + ty * 4 + i) * D_ + d0 + tx * 4] = o;
  }
}

// ---------------------------------------------------------------------------
// Kernel 5: out[b,s,d] = bproj[d] + sum_j V_all[b,s,j] * P[b,j,d]
// grid = B*(S/64)*(D/64) = 1024 blocks, 256 threads.
// ---------------------------------------------------------------------------
__global__ __launch_bounds__(256) void out_kernel(
    const float* __restrict__ Vall, const float* __restrict__ P,
    const float* __restrict__ bproj, float* __restrict__ out) {
  const int blk = blockIdx.x;
  const int dtile = blk & 15;
  const int stile = (blk >> 4) & 31;
  const int b = blk >> 9;
  const int s0 = stile * 64, d0 = dtile * 64;
  const int tid = threadIdx.x;
  const int tx = tid & 15, ty = tid >> 4;
  __shared__ float Vsh[32][68];  // [k][m], transposed on store
  __shared__ float Psh[32][64];  // [k][n]
  float acc[4][4] = {};
  for (int k0 = 0; k0 < HD_; k0 += 32) {
#pragma unroll
    for (int i = 0; i < 8; ++i) {
      int idx = tid + i * 256;
      int r = idx >> 5, c = idx & 31;
      Vsh[c][r] = Vall[(size_t)(b * S_ + s0 + r) * HD_ + k0 + c];
    }
#pragma unroll
    for (int i = 0; i < 8; ++i) {
      int idx = tid + i * 256;
      int r = idx >> 6, c = idx & 63;
      Psh[r][c] = P[(size_t)(b * HD_ + k0 + r) * D_ + d0 + c];
    }
    __syncthreads();
#pragma unroll
    for (int kk = 0; kk < 32; ++kk) {
      const float4 a4 = *(const float4*)&Vsh[kk][ty * 4];
      const float4 b4 = *(const float4*)&Psh[kk][tx * 4];
      const float a[4] = {a4.x, a4.y, a4.z, a4.w};
      const float bb[4] = {b4.x, b4.y, b4.z, b4.w};
#pragma unroll
      for (int i = 0; i < 4; ++i)
#pragma unroll
        for (int j = 0; j < 4; ++j) acc[i][j] += a[i] * bb[j];
    }
    __syncthreads();
  }
#pragma unroll
  for (int i = 0; i < 4; ++i) {
    float4 o;
    o.x = acc[i][0] + bproj[d0 + tx * 4 + 0];
    o.y = acc[i][1] + bproj[d0 + tx * 4 + 1];
    o.z = acc[i][2] + bproj[d0 + tx * 4 + 2];
    o.w = acc[i][3] + bproj[d0 + tx * 4 + 3];
    *(float4*)&out[(size_t)(b * S_ + s0 + ty * 4 + i) * D_ + d0 + tx * 4] = o;
  }
}

extern "C" void kernel_launch(void* const* d_in, const int* in_sizes, int n_in,
                              void* d_out, int out_size, void* d_ws, size_t ws_size,
                              hipStream_t stream) {
  const float* x = (const float*)d_in[0];
  const float* Wk = (const float*)d_in[1];
  const float* Wv = (const float*)d_in[2];
  const float* Wproj = (const float*)d_in[3];
  const float* bproj = (const float*)d_in[4];
  float* out = (float*)d_out;

  float* ws = (float*)d_ws;
  float* Vall = ws;                      // B*S*HD          = 4,194,304 floats
  float* Kall = Vall + (size_t)B_ * S_ * HD_;        // 4,194,304
  float* Mpart = Kall + (size_t)B_ * S_ * HD_;       // SPLIT*B*H*64*64 = 1,048,576
  float* M = Mpart + (size_t)SPLIT * B_ * H_ * HS_ * HS_;  // 131,072
  float* P = M + (size_t)B_ * H_ * HS_ * HS_;        // B*HD*D = 2,097,152
  // total ~11.67M floats = ~46.7 MB of d_ws; every element written before read.

  kv_proj_kernel<<<dim3(B_ * H_ * (S_ / 64)), dim3(256), 0, stream>>>(x, Wk, Wv, Kall, Vall);
  m_partial_kernel<<<dim3(SPLIT * B_ * H_), dim3(256), 0, stream>>>(Kall, Vall, Mpart);
  m_reduce_kernel<<<dim3(B_ * H_), dim3(256), 0, stream>>>(Mpart, M);
  p_kernel<<<dim3(B_ * H_ * (D_ / 64)), dim3(256), 0, stream>>>(M, Wproj, P);
  out_kernel<<<dim3(B_ * (S_ / 64) * (D_ / 64)), dim3(256), 0, stream>>>(Vall, P, bproj, out);
}

// Round 2
// 157.424 us; speedup vs baseline: 2.9966x; 2.9966x over previous
//
#include <hip/hip_runtime.h>

// Shapes (fixed by the problem)
#define B_ 2
#define S_ 2048
#define D_ 1024
#define H_ 16
#define HS_ 64
#define HD_ 1024   // H_*HS_
#define SPLIT 8    // S-split for the K^T V reduction
#define BS_ (B_*S_)  // 4096 flattened rows

typedef __attribute__((ext_vector_type(8))) short short8_t;   // 8 bf16 = 4 VGPRs (MFMA A/B frag)
typedef __attribute__((ext_vector_type(4))) float float4_t;   // MFMA C/D frag

__device__ inline unsigned short f32_to_bf16(float f) {
  unsigned int u = __float_as_uint(f);
  u += 0x7FFF + ((u >> 16) & 1);   // round-to-nearest-even
  return (unsigned short)(u >> 16);
}
__device__ inline float bf16_to_f32(unsigned short s) {
  return __uint_as_float(((unsigned int)s) << 16);
}

// async global->LDS, 16B per lane. LDS dest is wave-uniform base + lane*16.
__device__ inline void async_copy16(const void* g, void* lds) {
  __builtin_amdgcn_global_load_lds(
      (const __attribute__((address_space(1))) void*)g,
      (__attribute__((address_space(3))) void*)lds, 16, 0, 0);
}

// ---------------------------------------------------------------------------
// Convert x (fp32 [4096][1024]) -> bf16. 4 elems/thread.
// ---------------------------------------------------------------------------
__global__ __launch_bounds__(256) void convert_x_kernel(
    const float* __restrict__ x, unsigned short* __restrict__ xb) {
  int idx = blockIdx.x * 256 + threadIdx.x;          // 1M threads
  float4 v = ((const float4*)x)[idx];
  ushort4 o;
  o.x = f32_to_bf16(v.x); o.y = f32_to_bf16(v.y);
  o.z = f32_to_bf16(v.z); o.w = f32_to_bf16(v.w);
  ((ushort4*)xb)[idx] = o;
}

// ---------------------------------------------------------------------------
// Build Wkvt[h][n][d] bf16: n<64 -> Wk[h][d][n], n>=64 -> Wv[h][d][n-64].
// Transposed so kv_mfma's B operand is k(d)-contiguous. LDS 64x64 transpose.
// grid = H * (D/64) = 256 blocks.
// ---------------------------------------------------------------------------
__global__ __launch_bounds__(256) void wkvt_kernel(
    const float* __restrict__ Wk, const float* __restrict__ Wv,
    unsigned short* __restrict__ Wkvt) {
  const int h = blockIdx.x >> 4;
  const int d0 = (blockIdx.x & 15) * 64;
  const int tid = threadIdx.x;
  __shared__ float lds[64][65];
  // K half
#pragma unroll
  for (int i = 0; i < 16; ++i) {
    int idx = tid + i * 256; int dd = idx >> 6, e = idx & 63;
    lds[e][dd] = Wk[((size_t)h * D_ + d0 + dd) * HS_ + e];
  }
  __syncthreads();
#pragma unroll
  for (int i = 0; i < 16; ++i) {
    int idx = tid + i * 256; int e = idx >> 6, dd = idx & 63;
    Wkvt[((size_t)h * 128 + e) * D_ + d0 + dd] = f32_to_bf16(lds[e][dd]);
  }
  __syncthreads();
  // V half
#pragma unroll
  for (int i = 0; i < 16; ++i) {
    int idx = tid + i * 256; int dd = idx >> 6, e = idx & 63;
    lds[e][dd] = Wv[((size_t)h * D_ + d0 + dd) * HS_ + e];
  }
  __syncthreads();
#pragma unroll
  for (int i = 0; i < 16; ++i) {
    int idx = tid + i * 256; int e = idx >> 6, dd = idx & 63;
    Wkvt[((size_t)h * 128 + 64 + e) * D_ + d0 + dd] = f32_to_bf16(lds[e][dd]);
  }
}

// ---------------------------------------------------------------------------
// kv_mfma: C[128 s x 128 (64 K | 64 V)] per (stile,h). m97 structure.
// grid = 32 * 16 = 512 blocks, 256 threads (4 waves, 2x2 of 64x64).
// ---------------------------------------------------------------------------
__global__ __launch_bounds__(256) void kv_mfma_kernel(
    const unsigned short* __restrict__ xb,    // [4096][1024]
    const unsigned short* __restrict__ Wkvt,  // [16][128][1024]
    unsigned short* __restrict__ Kb,          // [4096][1024]
    unsigned short* __restrict__ Vb) {        // [4096][1024]
  const int blk = blockIdx.x;
  const int stile = blk & 31;
  const int h = blk >> 5;
  const int s0 = stile * 128;
  const int tid = threadIdx.x;
  const int lane = tid & 63;
  const int wid = tid >> 6;
  const int wm = wid & 1, wn = wid >> 1;
  const int quad = lane >> 4, l16 = lane & 15;
  const int arow = lane >> 2;          // 16 rows per copy instr
  const int acol = (lane & 3) * 8;     // 8 bf16 = 16B per lane

  __shared__ __align__(16) unsigned short As[128 * 32];  // [m][k]
  __shared__ __align__(16) unsigned short Bs[128 * 32];  // [n][k]

  float4_t acc[4][4];
  const float4_t fz = {0.f, 0.f, 0.f, 0.f};
#pragma unroll
  for (int i = 0; i < 4; ++i)
#pragma unroll
    for (int j = 0; j < 4; ++j) acc[i][j] = fz;

  for (int k0 = 0; k0 < D_; k0 += 32) {
#pragma unroll
    for (int i = 0; i < 2; ++i) {
      int r = wid * 32 + i * 16 + arow;
      async_copy16(xb + (size_t)(s0 + r) * D_ + k0 + acol,
                   As + (wid * 32 + i * 16) * 32);
      async_copy16(Wkvt + ((size_t)h * 128 + r) * D_ + k0 + acol,
                   Bs + (wid * 32 + i * 16) * 32);
    }
    __syncthreads();
    short8_t a[4], b[4];
#pragma unroll
    for (int mi = 0; mi < 4; ++mi)
      a[mi] = *(const short8_t*)(As + (wm * 64 + mi * 16 + l16) * 32 + quad * 8);
#pragma unroll
    for (int ni = 0; ni < 4; ++ni)
      b[ni] = *(const short8_t*)(Bs + (wn * 64 + ni * 16 + l16) * 32 + quad * 8);
#pragma unroll
    for (int mi = 0; mi < 4; ++mi)
#pragma unroll
      for (int ni = 0; ni < 4; ++ni)
        acc[mi][ni] = __builtin_amdgcn_mfma_f32_16x16x32_bf16(
            a[mi], b[ni], acc[mi][ni], 0, 0, 0);
    __syncthreads();
  }
  // Epilogue: wn==0 waves hold K columns, wn==1 hold V (wave-uniform).
  unsigned short* dst = (wn == 0) ? Kb : Vb;
#pragma unroll
  for (int mi = 0; mi < 4; ++mi)
#pragma unroll
    for (int ni = 0; ni < 4; ++ni) {
      int c = h * 64 + ni * 16 + l16;           // col within K or V
      int rowb = s0 + wm * 64 + mi * 16 + quad * 4;
#pragma unroll
      for (int r = 0; r < 4; ++r)
        dst[(size_t)(rowb + r) * HD_ + c] = f32_to_bf16(acc[mi][ni][r]);
    }
}

// ---------------------------------------------------------------------------
// m_partial: Mpart[split,b,h,f,e] = sum_{s slice} K[s,f]*V[s,e] (bf16 in, f32 acc)
// grid = SPLIT*B*H = 256 blocks.
// ---------------------------------------------------------------------------
__global__ __launch_bounds__(256) void m_partial_kernel(
    const unsigned short* __restrict__ Kb, const unsigned short* __restrict__ Vb,
    float* __restrict__ Mpart) {
  const int blk = blockIdx.x;
  const int h = blk & 15;
  const int b = (blk >> 4) & 1;
  const int split = blk >> 5;
  const int tid = threadIdx.x;
  const int tx = tid & 15, ty = tid >> 4;
  __shared__ float Ks[64][68];
  __shared__ float Vs[64][68];
  float acc[4][4] = {};
  const int sBase = split * (S_ / SPLIT);
  for (int sc = 0; sc < S_ / SPLIT; sc += 64) {
#pragma unroll
    for (int i = 0; i < 16; ++i) {
      int idx = tid + i * 256;
      int r = idx >> 6, c = idx & 63;
      size_t g = (size_t)(b * S_ + sBase + sc + r) * HD_ + h * HS_ + c;
      Ks[r][c] = bf16_to_f32(Kb[g]);
      Vs[r][c] = bf16_to_f32(Vb[g]);
    }
    __syncthreads();
#pragma unroll
    for (int ss = 0; ss < 64; ++ss) {
      const float4 a4 = *(const float4*)&Ks[ss][ty * 4];
      const float4 b4 = *(const float4*)&Vs[ss][tx * 4];
      const float a[4] = {a4.x, a4.y, a4.z, a4.w};
      const float bb[4] = {b4.x, b4.y, b4.z, b4.w};
#pragma unroll
      for (int i = 0; i < 4; ++i)
#pragma unroll
        for (int j = 0; j < 4; ++j) acc[i][j] += a[i] * bb[j];
    }
    __syncthreads();
  }
  float* dst = Mpart + ((size_t)(split * B_ + b) * H_ + h) * HS_ * HS_;
#pragma unroll
  for (int i = 0; i < 4; ++i) {
    float4 o = {acc[i][0], acc[i][1], acc[i][2], acc[i][3]};
    *(float4*)&dst[(ty * 4 + i) * HS_ + tx * 4] = o;
  }
}

// ---------------------------------------------------------------------------
// m_reduce: sum SPLIT partials, apply 0.125 scale. grid = B*H = 32.
// ---------------------------------------------------------------------------
__global__ __launch_bounds__(256) void m_reduce_kernel(
    const float* __restrict__ Mpart, float* __restrict__ M) {
  const int bh = blockIdx.x;
  const int tid = threadIdx.x;
  for (int idx = tid; idx < HS_ * HS_; idx += 256) {
    float s = 0.f;
#pragma unroll
    for (int p = 0; p < SPLIT; ++p)
      s += Mpart[((size_t)(p * B_ * H_) + bh) * (HS_ * HS_) + idx];
    M[(size_t)bh * (HS_ * HS_) + idx] = s * 0.125f;
  }
}

// ---------------------------------------------------------------------------
// p_kernel: P[b][h*64+f][d] = sum_e M[b,h,f,e]*Wproj[h*64+e][d], written
// TRANSPOSED as Pt[b][d][h*64+f] bf16 (k-contiguous for out_mfma staging).
// grid = B*H*(D/64) = 512 blocks.
// ---------------------------------------------------------------------------
__global__ __launch_bounds__(256) void p_kernel(
    const float* __restrict__ M, const float* __restrict__ Wproj,
    unsigned short* __restrict__ Pt) {
  const int blk = blockIdx.x;
  const int dtile = blk & 15;
  const int h = (blk >> 4) & 15;
  const int b = blk >> 8;
  const int d0 = dtile * 64;
  const int tid = threadIdx.x;
  const int tx = tid & 15, ty = tid >> 4;
  __shared__ float Ms[64][68];  // A: [e][f] (transposed on store)
  __shared__ float Ws[64][68];  // B: [e][d]
  const size_t mbase = ((size_t)(b * H_ + h)) * HS_ * HS_;
#pragma unroll
  for (int i = 0; i < 16; ++i) {
    int idx = tid + i * 256;
    int f = idx >> 6, e = idx & 63;
    Ms[e][f] = M[mbase + idx];
    Ws[f][e] = Wproj[(size_t)(h * HS_ + f) * D_ + d0 + e];
  }
  __syncthreads();
  float acc[4][4] = {};
#pragma unroll
  for (int kk = 0; kk < 64; ++kk) {
    const float4 a4 = *(const float4*)&Ms[kk][ty * 4];
    const float4 b4 = *(const float4*)&Ws[kk][tx * 4];
    const float a[4] = {a4.x, a4.y, a4.z, a4.w};
    const float bb[4] = {b4.x, b4.y, b4.z, b4.w};
#pragma unroll
    for (int i = 0; i < 4; ++i)
#pragma unroll
      for (int j = 0; j < 4; ++j) acc[i][j] += a[i] * bb[j];
  }
  // transpose through LDS: trans[c][r] = acc, then linear bf16 rows
  __syncthreads();
#pragma unroll
  for (int i = 0; i < 4; ++i)
#pragma unroll
    for (int j = 0; j < 4; ++j)
      Ms[tx * 4 + j][ty * 4 + i] = acc[i][j];
  __syncthreads();
  {
    int c = tid >> 2, ch = tid & 3;  // row c (d-dim), 16-elem chunk of f-dim
    unsigned short* dst = Pt + ((size_t)(b * D_ + d0 + c)) * HD_ + h * 64 + ch * 16;
#pragma unroll
    for (int e = 0; e < 16; ++e) dst[e] = f32_to_bf16(Ms[c][ch * 16 + e]);
  }
}

// ---------------------------------------------------------------------------
// out_mfma: out[s][d] = bproj[d] + sum_j Vb[s][j]*Pt[b][d][j].
// grid = 32 * 8 = 256 blocks, 128x128 tiles, K=1024.
// ---------------------------------------------------------------------------
__global__ __launch_bounds__(256) void out_mfma_kernel(
    const unsigned short* __restrict__ Vb,   // [4096][1024]
    const unsigned short* __restrict__ Pt,   // [2][1024][1024]
    const float* __restrict__ bproj,
    float* __restrict__ out) {
  const int blk = blockIdx.x;
  const int ntile = blk & 7;
  const int stile = blk >> 3;
  const int s0 = stile * 128;
  const int n0 = ntile * 128;
  const int b = s0 >> 11;  // s-tiles don't cross batch boundary
  const int tid = threadIdx.x;
  const int lane = tid & 63;
  const int wid = tid >> 6;
  const int wm = wid & 1, wn = wid >> 1;
  const int quad = lane >> 4, l16 = lane & 15;
  const int arow = lane >> 2;
  const int acol = (lane & 3) * 8;

  __shared__ __align__(16) unsigned short As[128 * 32];
  __shared__ __align__(16) unsigned short Bs[128 * 32];

  float4_t acc[4][4];
  const float4_t fz = {0.f, 0.f, 0.f, 0.f};
#pragma unroll
  for (int i = 0; i < 4; ++i)
#pragma unroll
    for (int j = 0; j < 4; ++j) acc[i][j] = fz;

  const unsigned short* Bpanel = Pt + (size_t)b * D_ * HD_;
  for (int k0 = 0; k0 < HD_; k0 += 32) {
#pragma unroll
    for (int i = 0; i < 2; ++i) {
      int r = wid * 32 + i * 16 + arow;
      async_copy16(Vb + (size_t)(s0 + r) * HD_ + k0 + acol,
                   As + (wid * 32 + i * 16) * 32);
      async_copy16(Bpanel + (size_t)(n0 + r) * HD_ + k0 + acol,
                   Bs + (wid * 32 + i * 16) * 32);
    }
    __syncthreads();
    short8_t a[4], bfr[4];
#pragma unroll
    for (int mi = 0; mi < 4; ++mi)
      a[mi] = *(const short8_t*)(As + (wm * 64 + mi * 16 + l16) * 32 + quad * 8);
#pragma unroll
    for (int ni = 0; ni < 4; ++ni)
      bfr[ni] = *(const short8_t*)(Bs + (wn * 64 + ni * 16 + l16) * 32 + quad * 8);
#pragma unroll
    for (int mi = 0; mi < 4; ++mi)
#pragma unroll
      for (int ni = 0; ni < 4; ++ni)
        acc[mi][ni] = __builtin_amdgcn_mfma_f32_16x16x32_bf16(
            a[mi], bfr[ni], acc[mi][ni], 0, 0, 0);
    __syncthreads();
  }
#pragma unroll
  for (int ni = 0; ni < 4; ++ni) {
    int col = n0 + wn * 64 + ni * 16 + l16;
    float bias = bproj[col];
#pragma unroll
    for (int mi = 0; mi < 4; ++mi) {
      int rowb = s0 + wm * 64 + mi * 16 + quad * 4;
#pragma unroll
      for (int r = 0; r < 4; ++r)
        out[(size_t)(rowb + r) * D_ + col] = acc[mi][ni][r] + bias;
    }
  }
}

extern "C" void kernel_launch(void* const* d_in, const int* in_sizes, int n_in,
                              void* d_out, int out_size, void* d_ws, size_t ws_size,
                              hipStream_t stream) {
  const float* x = (const float*)d_in[0];
  const float* Wk = (const float*)d_in[1];
  const float* Wv = (const float*)d_in[2];
  const float* Wproj = (const float*)d_in[3];
  const float* bproj = (const float*)d_in[4];
  float* out = (float*)d_out;

  // Workspace layout (36.5 MB total)
  char* ws = (char*)d_ws;
  unsigned short* xb = (unsigned short*)ws;                  // 4M bf16 = 8 MB
  unsigned short* Wkvt = xb + (size_t)BS_ * D_;              // 2M bf16 = 4 MB
  unsigned short* Kb = Wkvt + (size_t)H_ * 128 * D_;         // 4M bf16 = 8 MB
  unsigned short* Vb = Kb + (size_t)BS_ * HD_;               // 4M bf16 = 8 MB
  float* Mpart = (float*)(Vb + (size_t)BS_ * HD_);           // 1M f32 = 4 MB
  float* M = Mpart + (size_t)SPLIT * B_ * H_ * HS_ * HS_;    // 128K f32 = 0.5 MB
  unsigned short* Pt = (unsigned short*)(M + (size_t)B_ * H_ * HS_ * HS_);  // 2M bf16 = 4 MB

  convert_x_kernel<<<dim3(BS_ * D_ / 1024), dim3(256), 0, stream>>>(x, xb);
  wkvt_kernel<<<dim3(H_ * (D_ / 64)), dim3(256), 0, stream>>>(Wk, Wv, Wkvt);
  kv_mfma_kernel<<<dim3((BS_ / 128) * H_), dim3(256), 0, stream>>>(xb, Wkvt, Kb, Vb);
  m_partial_kernel<<<dim3(SPLIT * B_ * H_), dim3(256), 0, stream>>>(Kb, Vb, Mpart);
  m_reduce_kernel<<<dim3(B_ * H_), dim3(256), 0, stream>>>(Mpart, M);
  p_kernel<<<dim3(B_ * H_ * (D_ / 64)), dim3(256), 0, stream>>>(M, Wproj, Pt);
  out_mfma_kernel<<<dim3((BS_ / 128) * (D_ / 128)), dim3(256), 0, stream>>>(Vb, Pt, bproj, out);
}

// Round 3
// 150.931 us; speedup vs baseline: 3.1255x; 1.0430x over previous
//
#include <hip/hip_runtime.h>

// Shapes (fixed by the problem)
#define B_ 2
#define S_ 2048
#define D_ 1024
#define H_ 16
#define HS_ 64
#define HD_ 1024     // H_*HS_
#define SPLIT 16     // S-split for the K^T V reduction
#define BS_ (B_*S_)  // 4096 flattened rows
#define BK_ 64       // K-tile depth for MFMA kernels (16 iters over K=1024)

typedef __attribute__((ext_vector_type(8))) short short8_t;   // 8 bf16 = 4 VGPRs (MFMA A/B frag)
typedef __attribute__((ext_vector_type(4))) float float4_t;   // MFMA C/D frag

__device__ inline unsigned short f32_to_bf16(float f) {
  unsigned int u = __float_as_uint(f);
  u += 0x7FFF + ((u >> 16) & 1);   // round-to-nearest-even
  return (unsigned short)(u >> 16);
}
__device__ inline float bf16_to_f32(unsigned short s) {
  return __uint_as_float(((unsigned int)s) << 16);
}

// async global->LDS, 16B per lane. LDS dest is wave-uniform base + lane*16.
__device__ inline void async_copy16(const void* g, void* lds) {
  __builtin_amdgcn_global_load_lds(
      (const __attribute__((address_space(1))) void*)g,
      (__attribute__((address_space(3))) void*)lds, 16, 0, 0);
}

// ---------------------------------------------------------------------------
// prep: blocks [0,4096) convert x fp32->bf16 (4 elems/thread);
// blocks [4096,4352) build Wkvt[h][n][d] bf16 (n<64 -> Wk, n>=64 -> Wv),
// transposed so kv_mfma's B operand is k(d)-contiguous.
// ---------------------------------------------------------------------------
__global__ __launch_bounds__(256) void prep_kernel(
    const float* __restrict__ x, const float* __restrict__ Wk,
    const float* __restrict__ Wv, unsigned short* __restrict__ xb,
    unsigned short* __restrict__ Wkvt) {
  const int blk = blockIdx.x;
  const int tid = threadIdx.x;
  __shared__ float lds[64][65];
  if (blk < 4096) {
    int idx = blk * 256 + tid;
    float4 v = ((const float4*)x)[idx];
    ushort4 o;
    o.x = f32_to_bf16(v.x); o.y = f32_to_bf16(v.y);
    o.z = f32_to_bf16(v.z); o.w = f32_to_bf16(v.w);
    ((ushort4*)xb)[idx] = o;
    return;
  }
  const int wblk = blk - 4096;
  const int h = wblk >> 4;
  const int d0 = (wblk & 15) * 64;
  // K half
#pragma unroll
  for (int i = 0; i < 16; ++i) {
    int idx = tid + i * 256; int dd = idx >> 6, e = idx & 63;
    lds[e][dd] = Wk[((size_t)h * D_ + d0 + dd) * HS_ + e];
  }
  __syncthreads();
#pragma unroll
  for (int i = 0; i < 16; ++i) {
    int idx = tid + i * 256; int e = idx >> 6, dd = idx & 63;
    Wkvt[((size_t)h * 128 + e) * D_ + d0 + dd] = f32_to_bf16(lds[e][dd]);
  }
  __syncthreads();
  // V half
#pragma unroll
  for (int i = 0; i < 16; ++i) {
    int idx = tid + i * 256; int dd = idx >> 6, e = idx & 63;
    lds[e][dd] = Wv[((size_t)h * D_ + d0 + dd) * HS_ + e];
  }
  __syncthreads();
#pragma unroll
  for (int i = 0; i < 16; ++i) {
    int idx = tid + i * 256; int e = idx >> 6, dd = idx & 63;
    Wkvt[((size_t)h * 128 + 64 + e) * D_ + d0 + dd] = f32_to_bf16(lds[e][dd]);
  }
}

// ---------------------------------------------------------------------------
// kv_mfma: C[128 s x 128 (64 K | 64 V)] per (stile,h). BK=64 -> 16 K-iters.
// grid = 32 * 16 = 512 blocks (2/CU), 256 threads (4 waves as 2x2 of 64x64).
// ---------------------------------------------------------------------------
__global__ __launch_bounds__(256) void kv_mfma_kernel(
    const unsigned short* __restrict__ xb,    // [4096][1024]
    const unsigned short* __restrict__ Wkvt,  // [16][128][1024]
    unsigned short* __restrict__ Kb,          // [4096][1024]
    unsigned short* __restrict__ Vb) {        // [4096][1024]
  const int blk = blockIdx.x;
  const int stile = blk & 31;
  const int h = blk >> 5;
  const int s0 = stile * 128;
  const int tid = threadIdx.x;
  const int lane = tid & 63;
  const int wid = tid >> 6;
  const int wm = wid & 1, wn = wid >> 1;
  const int quad = lane >> 4, l16 = lane & 15;
  const int srow = lane >> 3;          // 8 rows per copy instr (128B rows)
  const int scol = (lane & 7) * 8;     // 8 bf16 = 16B per lane

  __shared__ __align__(16) unsigned short As[128 * BK_];  // [m][k] 16 KB
  __shared__ __align__(16) unsigned short Bs[128 * BK_];  // [n][k] 16 KB

  float4_t acc[4][4];
  const float4_t fz = {0.f, 0.f, 0.f, 0.f};
#pragma unroll
  for (int i = 0; i < 4; ++i)
#pragma unroll
    for (int j = 0; j < 4; ++j) acc[i][j] = fz;

  for (int k0 = 0; k0 < D_; k0 += BK_) {
#pragma unroll
    for (int i = 0; i < 4; ++i) {      // 16 row-groups of 8 for A and B each
      int g = wid * 4 + i;
      int r = g * 8 + srow;
      async_copy16(xb + (size_t)(s0 + r) * D_ + k0 + scol, As + g * 8 * BK_);
      async_copy16(Wkvt + ((size_t)h * 128 + r) * D_ + k0 + scol, Bs + g * 8 * BK_);
    }
    __syncthreads();
    short8_t a[4][2], b[4][2];
#pragma unroll
    for (int mi = 0; mi < 4; ++mi)
#pragma unroll
      for (int ks = 0; ks < 2; ++ks)
        a[mi][ks] = *(const short8_t*)(As + (wm * 64 + mi * 16 + l16) * BK_ +
                                       (ks * 4 + quad) * 8);
#pragma unroll
    for (int ni = 0; ni < 4; ++ni)
#pragma unroll
      for (int ks = 0; ks < 2; ++ks)
        b[ni][ks] = *(const short8_t*)(Bs + (wn * 64 + ni * 16 + l16) * BK_ +
                                       (ks * 4 + quad) * 8);
#pragma unroll
    for (int ks = 0; ks < 2; ++ks)
#pragma unroll
      for (int mi = 0; mi < 4; ++mi)
#pragma unroll
        for (int ni = 0; ni < 4; ++ni)
          acc[mi][ni] = __builtin_amdgcn_mfma_f32_16x16x32_bf16(
              a[mi][ks], b[ni][ks], acc[mi][ni], 0, 0, 0);
    __syncthreads();
  }
  // Epilogue: wn==0 waves hold K columns, wn==1 hold V (wave-uniform).
  unsigned short* dst = (wn == 0) ? Kb : Vb;
#pragma unroll
  for (int mi = 0; mi < 4; ++mi)
#pragma unroll
    for (int ni = 0; ni < 4; ++ni) {
      int c = h * 64 + ni * 16 + l16;
      int rowb = s0 + wm * 64 + mi * 16 + quad * 4;
#pragma unroll
      for (int r = 0; r < 4; ++r)
        dst[(size_t)(rowb + r) * HD_ + c] = f32_to_bf16(acc[mi][ni][r]);
    }
}

// ---------------------------------------------------------------------------
// m_partial: Mpart[split,b,h,f,e] = sum_{s slice} K[s,f]*V[s,e] (bf16 in, f32 acc)
// grid = SPLIT*B*H = 512 blocks (2/CU).
// ---------------------------------------------------------------------------
__global__ __launch_bounds__(256) void m_partial_kernel(
    const unsigned short* __restrict__ Kb, const unsigned short* __restrict__ Vb,
    float* __restrict__ Mpart) {
  const int blk = blockIdx.x;
  const int h = blk & 15;
  const int b = (blk >> 4) & 1;
  const int split = blk >> 5;
  const int tid = threadIdx.x;
  const int tx = tid & 15, ty = tid >> 4;
  __shared__ float Ks[64][68];
  __shared__ float Vs[64][68];
  float acc[4][4] = {};
  const int sBase = split * (S_ / SPLIT);
  for (int sc = 0; sc < S_ / SPLIT; sc += 64) {
#pragma unroll
    for (int i = 0; i < 16; ++i) {
      int idx = tid + i * 256;
      int r = idx >> 6, c = idx & 63;
      size_t g = (size_t)(b * S_ + sBase + sc + r) * HD_ + h * HS_ + c;
      Ks[r][c] = bf16_to_f32(Kb[g]);
      Vs[r][c] = bf16_to_f32(Vb[g]);
    }
    __syncthreads();
#pragma unroll
    for (int ss = 0; ss < 64; ++ss) {
      const float4 a4 = *(const float4*)&Ks[ss][ty * 4];
      const float4 b4 = *(const float4*)&Vs[ss][tx * 4];
      const float a[4] = {a4.x, a4.y, a4.z, a4.w};
      const float bb[4] = {b4.x, b4.y, b4.z, b4.w};
#pragma unroll
      for (int i = 0; i < 4; ++i)
#pragma unroll
        for (int j = 0; j < 4; ++j) acc[i][j] += a[i] * bb[j];
    }
    __syncthreads();
  }
  float* dst = Mpart + ((size_t)(split * B_ + b) * H_ + h) * HS_ * HS_;
#pragma unroll
  for (int i = 0; i < 4; ++i) {
    float4 o = {acc[i][0], acc[i][1], acc[i][2], acc[i][3]};
    *(float4*)&dst[(ty * 4 + i) * HS_ + tx * 4] = o;
  }
}

// ---------------------------------------------------------------------------
// m_reduce: sum SPLIT partials, apply 0.125 scale. grid = 128 blocks,
// 4 f32 per thread (float4).
// ---------------------------------------------------------------------------
__global__ __launch_bounds__(256) void m_reduce_kernel(
    const float* __restrict__ Mpart, float* __restrict__ M) {
  const int gid = blockIdx.x * 256 + threadIdx.x;
  const int e0 = gid * 4;               // [0, 131072)
  const int bh = e0 >> 12;
  const int idx = e0 & 4095;
  float4 s = {0.f, 0.f, 0.f, 0.f};
#pragma unroll
  for (int p = 0; p < SPLIT; ++p) {
    const float4 v = *(const float4*)&Mpart[((size_t)(p * B_ * H_) + bh) * 4096 + idx];
    s.x += v.x; s.y += v.y; s.z += v.z; s.w += v.w;
  }
  s.x *= 0.125f; s.y *= 0.125f; s.z *= 0.125f; s.w *= 0.125f;
  *(float4*)&M[(size_t)bh * 4096 + idx] = s;
}

// ---------------------------------------------------------------------------
// p_kernel: P[b][h*64+f][d] = sum_e M[b,h,f,e]*Wproj[h*64+e][d], written
// TRANSPOSED as Pt[b][d][h*64+f] bf16 (k-contiguous for out_mfma staging).
// grid = B*H*(D/64) = 512 blocks.
// ---------------------------------------------------------------------------
__global__ __launch_bounds__(256) void p_kernel(
    const float* __restrict__ M, const float* __restrict__ Wproj,
    unsigned short* __restrict__ Pt) {
  const int blk = blockIdx.x;
  const int dtile = blk & 15;
  const int h = (blk >> 4) & 15;
  const int b = blk >> 8;
  const int d0 = dtile * 64;
  const int tid = threadIdx.x;
  const int tx = tid & 15, ty = tid >> 4;
  __shared__ float Ms[64][68];  // A: [e][f] (transposed on store)
  __shared__ float Ws[64][68];  // B: [e][d]
  const size_t mbase = ((size_t)(b * H_ + h)) * HS_ * HS_;
#pragma unroll
  for (int i = 0; i < 16; ++i) {
    int idx = tid + i * 256;
    int f = idx >> 6, e = idx & 63;
    Ms[e][f] = M[mbase + idx];
    Ws[f][e] = Wproj[(size_t)(h * HS_ + f) * D_ + d0 + e];
  }
  __syncthreads();
  float acc[4][4] = {};
#pragma unroll
  for (int kk = 0; kk < 64; ++kk) {
    const float4 a4 = *(const float4*)&Ms[kk][ty * 4];
    const float4 b4 = *(const float4*)&Ws[kk][tx * 4];
    const float a[4] = {a4.x, a4.y, a4.z, a4.w};
    const float bb[4] = {b4.x, b4.y, b4.z, b4.w};
#pragma unroll
    for (int i = 0; i < 4; ++i)
#pragma unroll
      for (int j = 0; j < 4; ++j) acc[i][j] += a[i] * bb[j];
  }
  // transpose through LDS: trans[d][f] then linear bf16 rows
  __syncthreads();
#pragma unroll
  for (int i = 0; i < 4; ++i)
#pragma unroll
    for (int j = 0; j < 4; ++j)
      Ms[tx * 4 + j][ty * 4 + i] = acc[i][j];
  __syncthreads();
  {
    int c = tid >> 2, ch = tid & 3;  // row c (d-dim), 16-elem chunk of f-dim
    unsigned short* dst = Pt + ((size_t)(b * D_ + d0 + c)) * HD_ + h * 64 + ch * 16;
#pragma unroll
    for (int e = 0; e < 16; ++e) dst[e] = f32_to_bf16(Ms[c][ch * 16 + e]);
  }
}

// ---------------------------------------------------------------------------
// out_mfma: out[s][d] = bproj[d] + sum_j Vb[s][j]*Pt[b][d][j].
// 128x64 tiles -> grid = 32*16 = 512 blocks (2/CU), BK=64.
// 4 waves as 2(m)x2(n), each wave 64x32.
// ---------------------------------------------------------------------------
__global__ __launch_bounds__(256) void out_mfma_kernel(
    const unsigned short* __restrict__ Vb,   // [4096][1024]
    const unsigned short* __restrict__ Pt,   // [2][1024][1024]
    const float* __restrict__ bproj,
    float* __restrict__ out) {
  const int blk = blockIdx.x;
  const int ntile = blk & 15;              // 1024/64 = 16
  const int stile = blk >> 4;              // 4096/128 = 32
  const int s0 = stile * 128;
  const int n0 = ntile * 64;
  const int b = s0 >> 11;                  // s-tiles don't cross batch boundary
  const int tid = threadIdx.x;
  const int lane = tid & 63;
  const int wid = tid >> 6;
  const int wm = wid & 1, wn = wid >> 1;
  const int quad = lane >> 4, l16 = lane & 15;
  const int srow = lane >> 3;
  const int scol = (lane & 7) * 8;

  __shared__ __align__(16) unsigned short As[128 * BK_];  // 16 KB
  __shared__ __align__(16) unsigned short Bs[64 * BK_];   //  8 KB

  float4_t acc[4][2];
  const float4_t fz = {0.f, 0.f, 0.f, 0.f};
#pragma unroll
  for (int i = 0; i < 4; ++i)
#pragma unroll
    for (int j = 0; j < 2; ++j) acc[i][j] = fz;

  const unsigned short* Bpanel = Pt + (size_t)b * D_ * HD_;
  for (int k0 = 0; k0 < HD_; k0 += BK_) {
#pragma unroll
    for (int i = 0; i < 4; ++i) {        // A: 16 row-groups of 8
      int g = wid * 4 + i;
      int r = g * 8 + srow;
      async_copy16(Vb + (size_t)(s0 + r) * HD_ + k0 + scol, As + g * 8 * BK_);
    }
#pragma unroll
    for (int i = 0; i < 2; ++i) {        // B: 8 row-groups of 8
      int g = wid * 2 + i;
      int r = g * 8 + srow;
      async_copy16(Bpanel + (size_t)(n0 + r) * HD_ + k0 + scol, Bs + g * 8 * BK_);
    }
    __syncthreads();
    short8_t a[4][2], bfr[2][2];
#pragma unroll
    for (int mi = 0; mi < 4; ++mi)
#pragma unroll
      for (int ks = 0; ks < 2; ++ks)
        a[mi][ks] = *(const short8_t*)(As + (wm * 64 + mi * 16 + l16) * BK_ +
                                       (ks * 4 + quad) * 8);
#pragma unroll
    for (int ni = 0; ni < 2; ++ni)
#pragma unroll
      for (int ks = 0; ks < 2; ++ks)
        bfr[ni][ks] = *(const short8_t*)(Bs + (wn * 32 + ni * 16 + l16) * BK_ +
                                         (ks * 4 + quad) * 8);
#pragma unroll
    for (int ks = 0; ks < 2; ++ks)
#pragma unroll
      for (int mi = 0; mi < 4; ++mi)
#pragma unroll
        for (int ni = 0; ni < 2; ++ni)
          acc[mi][ni] = __builtin_amdgcn_mfma_f32_16x16x32_bf16(
              a[mi][ks], bfr[ni][ks], acc[mi][ni], 0, 0, 0);
    __syncthreads();
  }
#pragma unroll
  for (int ni = 0; ni < 2; ++ni) {
    int col = n0 + wn * 32 + ni * 16 + l16;
    float bias = bproj[col];
#pragma unroll
    for (int mi = 0; mi < 4; ++mi) {
      int rowb = s0 + wm * 64 + mi * 16 + quad * 4;
#pragma unroll
      for (int r = 0; r < 4; ++r)
        out[(size_t)(rowb + r) * D_ + col] = acc[mi][ni][r] + bias;
    }
  }
}

extern "C" void kernel_launch(void* const* d_in, const int* in_sizes, int n_in,
                              void* d_out, int out_size, void* d_ws, size_t ws_size,
                              hipStream_t stream) {
  const float* x = (const float*)d_in[0];
  const float* Wk = (const float*)d_in[1];
  const float* Wv = (const float*)d_in[2];
  const float* Wproj = (const float*)d_in[3];
  const float* bproj = (const float*)d_in[4];
  float* out = (float*)d_out;

  // Workspace layout (~40.5 MB total)
  char* ws = (char*)d_ws;
  unsigned short* xb = (unsigned short*)ws;                  // 4M bf16 = 8 MB
  unsigned short* Wkvt = xb + (size_t)BS_ * D_;              // 2M bf16 = 4 MB
  unsigned short* Kb = Wkvt + (size_t)H_ * 128 * D_;         // 4M bf16 = 8 MB
  unsigned short* Vb = Kb + (size_t)BS_ * HD_;               // 4M bf16 = 8 MB
  float* Mpart = (float*)(Vb + (size_t)BS_ * HD_);           // 2M f32 = 8 MB
  float* M = Mpart + (size_t)SPLIT * B_ * H_ * HS_ * HS_;    // 128K f32 = 0.5 MB
  unsigned short* Pt = (unsigned short*)(M + (size_t)B_ * H_ * HS_ * HS_);  // 2M bf16 = 4 MB

  prep_kernel<<<dim3(4096 + H_ * (D_ / 64)), dim3(256), 0, stream>>>(x, Wk, Wv, xb, Wkvt);
  kv_mfma_kernel<<<dim3((BS_ / 128) * H_), dim3(256), 0, stream>>>(xb, Wkvt, Kb, Vb);
  m_partial_kernel<<<dim3(SPLIT * B_ * H_), dim3(256), 0, stream>>>(Kb, Vb, Mpart);
  m_reduce_kernel<<<dim3(128), dim3(256), 0, stream>>>(Mpart, M);
  p_kernel<<<dim3(B_ * H_ * (D_ / 64)), dim3(256), 0, stream>>>(M, Wproj, Pt);
  out_mfma_kernel<<<dim3((BS_ / 128) * (D_ / 64)), dim3(256), 0, stream>>>(Vb, Pt, bproj, out);
}

// Round 4
// 145.127 us; speedup vs baseline: 3.2505x; 1.0400x over previous
//
#include <hip/hip_runtime.h>

// Shapes (fixed by the problem)
#define B_ 2
#define S_ 2048
#define D_ 1024
#define H_ 16
#define HS_ 64
#define HD_ 1024     // H_*HS_
#define SPLIT 16     // S-split for the K^T V reduction
#define BS_ (B_*S_)  // 4096 flattened rows
#define BK_ 64       // K-tile depth for MFMA kernels (16 iters over K=1024)

typedef __attribute__((ext_vector_type(8))) short short8_t;            // 8 bf16 (MFMA A/B frag)
typedef __attribute__((ext_vector_type(8))) unsigned short ushort8_t;  // 16B bf16 load
typedef __attribute__((ext_vector_type(4))) float float4_t;            // MFMA C/D frag

__device__ inline unsigned short f32_to_bf16(float f) {
  unsigned int u = __float_as_uint(f);
  u += 0x7FFF + ((u >> 16) & 1);   // round-to-nearest-even
  return (unsigned short)(u >> 16);
}
__device__ inline float bf16_to_f32(unsigned short s) {
  return __uint_as_float(((unsigned int)s) << 16);
}

// async global->LDS, 16B per lane. LDS dest is wave-uniform base + lane*16.
__device__ inline void async_copy16(const void* g, void* lds) {
  __builtin_amdgcn_global_load_lds(
      (const __attribute__((address_space(1))) void*)g,
      (__attribute__((address_space(3))) void*)lds, 16, 0, 0);
}

// LDS XOR swizzle: LDS[row][chunk c] holds global chunk (c ^ (row&7)).
// Staging: lane (chunk c = lane&7, row r = base + lane>>3) loads global chunk
// c ^ (r&7). Fragment read of logical chunk q from row R is at physical chunk
// q ^ (R&7). With R ≡ l16 (mod 8) across a 16-lane group, reads sweep all 32
// banks -> 2 lanes/bank = conflict-free (m136).

// ---------------------------------------------------------------------------
// prep: blocks [0,4096) convert x fp32->bf16 (4 elems/thread);
// blocks [4096,4352) build Wkvt[h][n][d] bf16 (n<64 -> Wk, n>=64 -> Wv),
// transposed so kv_mfma's B operand is k(d)-contiguous.
// ---------------------------------------------------------------------------
__global__ __launch_bounds__(256) void prep_kernel(
    const float* __restrict__ x, const float* __restrict__ Wk,
    const float* __restrict__ Wv, unsigned short* __restrict__ xb,
    unsigned short* __restrict__ Wkvt) {
  const int blk = blockIdx.x;
  const int tid = threadIdx.x;
  __shared__ float lds[64][65];
  if (blk < 4096) {
    int idx = blk * 256 + tid;
    float4 v = ((const float4*)x)[idx];
    ushort4 o;
    o.x = f32_to_bf16(v.x); o.y = f32_to_bf16(v.y);
    o.z = f32_to_bf16(v.z); o.w = f32_to_bf16(v.w);
    ((ushort4*)xb)[idx] = o;
    return;
  }
  const int wblk = blk - 4096;
  const int h = wblk >> 4;
  const int d0 = (wblk & 15) * 64;
  // K half
#pragma unroll
  for (int i = 0; i < 16; ++i) {
    int idx = tid + i * 256; int dd = idx >> 6, e = idx & 63;
    lds[e][dd] = Wk[((size_t)h * D_ + d0 + dd) * HS_ + e];
  }
  __syncthreads();
#pragma unroll
  for (int i = 0; i < 16; ++i) {
    int idx = tid + i * 256; int e = idx >> 6, dd = idx & 63;
    Wkvt[((size_t)h * 128 + e) * D_ + d0 + dd] = f32_to_bf16(lds[e][dd]);
  }
  __syncthreads();
  // V half
#pragma unroll
  for (int i = 0; i < 16; ++i) {
    int idx = tid + i * 256; int dd = idx >> 6, e = idx & 63;
    lds[e][dd] = Wv[((size_t)h * D_ + d0 + dd) * HS_ + e];
  }
  __syncthreads();
#pragma unroll
  for (int i = 0; i < 16; ++i) {
    int idx = tid + i * 256; int e = idx >> 6, dd = idx & 63;
    Wkvt[((size_t)h * 128 + 64 + e) * D_ + d0 + dd] = f32_to_bf16(lds[e][dd]);
  }
}

// ---------------------------------------------------------------------------
// kv_mfma: C[128 s x 128 (64 K | 64 V)] per (stile,h). BK=64, swizzled LDS.
// grid = 32 * 16 = 512 blocks (2/CU), 256 threads (4 waves as 2x2 of 64x64).
// ---------------------------------------------------------------------------
__global__ __launch_bounds__(256) void kv_mfma_kernel(
    const unsigned short* __restrict__ xb,    // [4096][1024]
    const unsigned short* __restrict__ Wkvt,  // [16][128][1024]
    unsigned short* __restrict__ Kb,          // [4096][1024]
    unsigned short* __restrict__ Vb) {        // [4096][1024]
  const int blk = blockIdx.x;
  const int stile = blk & 31;
  const int h = blk >> 5;
  const int s0 = stile * 128;
  const int tid = threadIdx.x;
  const int lane = tid & 63;
  const int wid = tid >> 6;
  const int wm = wid & 1, wn = wid >> 1;
  const int quad = lane >> 4, l16 = lane & 15;
  const int srow8 = lane >> 3;                     // staging row within group
  const int csw = ((lane & 7) ^ srow8) * 8;        // swizzled global chunk (elems)
  const int xa = l16 & 7;                          // frag-read swizzle key

  __shared__ __align__(16) unsigned short As[128 * BK_];  // [m][k] 16 KB
  __shared__ __align__(16) unsigned short Bs[128 * BK_];  // [n][k] 16 KB

  float4_t acc[4][4];
  const float4_t fz = {0.f, 0.f, 0.f, 0.f};
#pragma unroll
  for (int i = 0; i < 4; ++i)
#pragma unroll
    for (int j = 0; j < 4; ++j) acc[i][j] = fz;

  for (int k0 = 0; k0 < D_; k0 += BK_) {
#pragma unroll
    for (int i = 0; i < 4; ++i) {      // 16 row-groups of 8 for A and B each
      int g = wid * 4 + i;
      int r = g * 8 + srow8;
      async_copy16(xb + (size_t)(s0 + r) * D_ + k0 + csw, As + g * 8 * BK_);
      async_copy16(Wkvt + ((size_t)h * 128 + r) * D_ + k0 + csw, Bs + g * 8 * BK_);
    }
    __syncthreads();
    short8_t a[4][2], b[4][2];
#pragma unroll
    for (int mi = 0; mi < 4; ++mi)
#pragma unroll
      for (int ks = 0; ks < 2; ++ks)
        a[mi][ks] = *(const short8_t*)(As + (wm * 64 + mi * 16 + l16) * BK_ +
                                       ((ks * 4 + quad) ^ xa) * 8);
#pragma unroll
    for (int ni = 0; ni < 4; ++ni)
#pragma unroll
      for (int ks = 0; ks < 2; ++ks)
        b[ni][ks] = *(const short8_t*)(Bs + (wn * 64 + ni * 16 + l16) * BK_ +
                                       ((ks * 4 + quad) ^ xa) * 8);
#pragma unroll
    for (int ks = 0; ks < 2; ++ks)
#pragma unroll
      for (int mi = 0; mi < 4; ++mi)
#pragma unroll
        for (int ni = 0; ni < 4; ++ni)
          acc[mi][ni] = __builtin_amdgcn_mfma_f32_16x16x32_bf16(
              a[mi][ks], b[ni][ks], acc[mi][ni], 0, 0, 0);
    __syncthreads();
  }
  // Epilogue: wn==0 waves hold K columns, wn==1 hold V (wave-uniform).
  unsigned short* dst = (wn == 0) ? Kb : Vb;
#pragma unroll
  for (int mi = 0; mi < 4; ++mi)
#pragma unroll
    for (int ni = 0; ni < 4; ++ni) {
      int c = h * 64 + ni * 16 + l16;
      int rowb = s0 + wm * 64 + mi * 16 + quad * 4;
#pragma unroll
      for (int r = 0; r < 4; ++r)
        dst[(size_t)(rowb + r) * HD_ + c] = f32_to_bf16(acc[mi][ni][r]);
    }
}

// ---------------------------------------------------------------------------
// m_partial: Mpart[split,b,h,f,e] = sum_{s slice} K[s,f]*V[s,e] (bf16 in, f32 acc)
// grid = SPLIT*B*H = 512 blocks (2/CU). 16B vector loads.
// ---------------------------------------------------------------------------
__global__ __launch_bounds__(256) void m_partial_kernel(
    const unsigned short* __restrict__ Kb, const unsigned short* __restrict__ Vb,
    float* __restrict__ Mpart) {
  const int blk = blockIdx.x;
  const int h = blk & 15;
  const int b = (blk >> 4) & 1;
  const int split = blk >> 5;
  const int tid = threadIdx.x;
  const int tx = tid & 15, ty = tid >> 4;
  __shared__ float Ks[64][68];
  __shared__ float Vs[64][68];
  float acc[4][4] = {};
  const int sBase = split * (S_ / SPLIT);
  for (int sc = 0; sc < S_ / SPLIT; sc += 64) {
#pragma unroll
    for (int i = 0; i < 2; ++i) {      // 512 chunks of 8 bf16 (16B)
      int ch = tid + i * 256;
      int r = ch >> 3, c = (ch & 7) * 8;
      size_t g = (size_t)(b * S_ + sBase + sc + r) * HD_ + h * HS_ + c;
      ushort8_t k8 = *(const ushort8_t*)(Kb + g);
      ushort8_t v8 = *(const ushort8_t*)(Vb + g);
#pragma unroll
      for (int j = 0; j < 8; ++j) {
        Ks[r][c + j] = bf16_to_f32(k8[j]);
        Vs[r][c + j] = bf16_to_f32(v8[j]);
      }
    }
    __syncthreads();
#pragma unroll
    for (int ss = 0; ss < 64; ++ss) {
      const float4 a4 = *(const float4*)&Ks[ss][ty * 4];
      const float4 b4 = *(const float4*)&Vs[ss][tx * 4];
      const float a[4] = {a4.x, a4.y, a4.z, a4.w};
      const float bb[4] = {b4.x, b4.y, b4.z, b4.w};
#pragma unroll
      for (int i = 0; i < 4; ++i)
#pragma unroll
        for (int j = 0; j < 4; ++j) acc[i][j] += a[i] * bb[j];
    }
    __syncthreads();
  }
  float* dst = Mpart + ((size_t)(split * B_ + b) * H_ + h) * HS_ * HS_;
#pragma unroll
  for (int i = 0; i < 4; ++i) {
    float4 o = {acc[i][0], acc[i][1], acc[i][2], acc[i][3]};
    *(float4*)&dst[(ty * 4 + i) * HS_ + tx * 4] = o;
  }
}

// ---------------------------------------------------------------------------
// m_reduce: sum SPLIT partials, apply 0.125 scale. grid = 128 blocks.
// ---------------------------------------------------------------------------
__global__ __launch_bounds__(256) void m_reduce_kernel(
    const float* __restrict__ Mpart, float* __restrict__ M) {
  const int gid = blockIdx.x * 256 + threadIdx.x;
  const int e0 = gid * 4;               // [0, 131072)
  const int bh = e0 >> 12;
  const int idx = e0 & 4095;
  float4 s = {0.f, 0.f, 0.f, 0.f};
#pragma unroll
  for (int p = 0; p < SPLIT; ++p) {
    const float4 v = *(const float4*)&Mpart[((size_t)(p * B_ * H_) + bh) * 4096 + idx];
    s.x += v.x; s.y += v.y; s.z += v.z; s.w += v.w;
  }
  s.x *= 0.125f; s.y *= 0.125f; s.z *= 0.125f; s.w *= 0.125f;
  *(float4*)&M[(size_t)bh * 4096 + idx] = s;
}

// ---------------------------------------------------------------------------
// p_kernel: P[b][h*64+f][d] = sum_e M[b,h,f,e]*Wproj[h*64+e][d], written
// TRANSPOSED as Pt[b][d][h*64+f] bf16 (k-contiguous for out_mfma staging).
// grid = B*H*(D/64) = 512 blocks.
// ---------------------------------------------------------------------------
__global__ __launch_bounds__(256) void p_kernel(
    const float* __restrict__ M, const float* __restrict__ Wproj,
    unsigned short* __restrict__ Pt) {
  const int blk = blockIdx.x;
  const int dtile = blk & 15;
  const int h = (blk >> 4) & 15;
  const int b = blk >> 8;
  const int d0 = dtile * 64;
  const int tid = threadIdx.x;
  const int tx = tid & 15, ty = tid >> 4;
  __shared__ float Ms[64][68];  // A: [e][f] (transposed on store)
  __shared__ float Ws[64][68];  // B: [e][d]
  const size_t mbase = ((size_t)(b * H_ + h)) * HS_ * HS_;
#pragma unroll
  for (int i = 0; i < 16; ++i) {
    int idx = tid + i * 256;
    int f = idx >> 6, e = idx & 63;
    Ms[e][f] = M[mbase + idx];
    Ws[f][e] = Wproj[(size_t)(h * HS_ + f) * D_ + d0 + e];
  }
  __syncthreads();
  float acc[4][4] = {};
#pragma unroll
  for (int kk = 0; kk < 64; ++kk) {
    const float4 a4 = *(const float4*)&Ms[kk][ty * 4];
    const float4 b4 = *(const float4*)&Ws[kk][tx * 4];
    const float a[4] = {a4.x, a4.y, a4.z, a4.w};
    const float bb[4] = {b4.x, b4.y, b4.z, b4.w};
#pragma unroll
    for (int i = 0; i < 4; ++i)
#pragma unroll
      for (int j = 0; j < 4; ++j) acc[i][j] += a[i] * bb[j];
  }
  // transpose through LDS: trans[d][f] then linear bf16 rows
  __syncthreads();
#pragma unroll
  for (int i = 0; i < 4; ++i)
#pragma unroll
    for (int j = 0; j < 4; ++j)
      Ms[tx * 4 + j][ty * 4 + i] = acc[i][j];
  __syncthreads();
  {
    int c = tid >> 2, ch = tid & 3;  // row c (d-dim), 16-elem chunk of f-dim
    unsigned short* dst = Pt + ((size_t)(b * D_ + d0 + c)) * HD_ + h * 64 + ch * 16;
#pragma unroll
    for (int e = 0; e < 16; ++e) dst[e] = f32_to_bf16(Ms[c][ch * 16 + e]);
  }
}

// ---------------------------------------------------------------------------
// out_mfma: out[s][d] = bproj[d] + sum_j Vb[s][j]*Pt[b][d][j].
// 128x64 tiles -> grid = 32*16 = 512 blocks (2/CU), BK=64, swizzled LDS.
// 4 waves as 2(m)x2(n), each wave 64x32.
// ---------------------------------------------------------------------------
__global__ __launch_bounds__(256) void out_mfma_kernel(
    const unsigned short* __restrict__ Vb,   // [4096][1024]
    const unsigned short* __restrict__ Pt,   // [2][1024][1024]
    const float* __restrict__ bproj,
    float* __restrict__ out) {
  const int blk = blockIdx.x;
  const int ntile = blk & 15;              // 1024/64 = 16
  const int stile = blk >> 4;              // 4096/128 = 32
  const int s0 = stile * 128;
  const int n0 = ntile * 64;
  const int b = s0 >> 11;                  // s-tiles don't cross batch boundary
  const int tid = threadIdx.x;
  const int lane = tid & 63;
  const int wid = tid >> 6;
  const int wm = wid & 1, wn = wid >> 1;
  const int quad = lane >> 4, l16 = lane & 15;
  const int srow8 = lane >> 3;
  const int csw = ((lane & 7) ^ srow8) * 8;
  const int xa = l16 & 7;

  __shared__ __align__(16) unsigned short As[128 * BK_];  // 16 KB
  __shared__ __align__(16) unsigned short Bs[64 * BK_];   //  8 KB

  float4_t acc[4][2];
  const float4_t fz = {0.f, 0.f, 0.f, 0.f};
#pragma unroll
  for (int i = 0; i < 4; ++i)
#pragma unroll
    for (int j = 0; j < 2; ++j) acc[i][j] = fz;

  const unsigned short* Bpanel = Pt + (size_t)b * D_ * HD_;
  for (int k0 = 0; k0 < HD_; k0 += BK_) {
#pragma unroll
    for (int i = 0; i < 4; ++i) {        // A: 16 row-groups of 8
      int g = wid * 4 + i;
      int r = g * 8 + srow8;
      async_copy16(Vb + (size_t)(s0 + r) * HD_ + k0 + csw, As + g * 8 * BK_);
    }
#pragma unroll
    for (int i = 0; i < 2; ++i) {        // B: 8 row-groups of 8
      int g = wid * 2 + i;
      int r = g * 8 + srow8;
      async_copy16(Bpanel + (size_t)(n0 + r) * HD_ + k0 + csw, Bs + g * 8 * BK_);
    }
    __syncthreads();
    short8_t a[4][2], bfr[2][2];
#pragma unroll
    for (int mi = 0; mi < 4; ++mi)
#pragma unroll
      for (int ks = 0; ks < 2; ++ks)
        a[mi][ks] = *(const short8_t*)(As + (wm * 64 + mi * 16 + l16) * BK_ +
                                       ((ks * 4 + quad) ^ xa) * 8);
#pragma unroll
    for (int ni = 0; ni < 2; ++ni)
#pragma unroll
      for (int ks = 0; ks < 2; ++ks)
        bfr[ni][ks] = *(const short8_t*)(Bs + (wn * 32 + ni * 16 + l16) * BK_ +
                                         ((ks * 4 + quad) ^ xa) * 8);
#pragma unroll
    for (int ks = 0; ks < 2; ++ks)
#pragma unroll
      for (int mi = 0; mi < 4; ++mi)
#pragma unroll
        for (int ni = 0; ni < 2; ++ni)
          acc[mi][ni] = __builtin_amdgcn_mfma_f32_16x16x32_bf16(
              a[mi][ks], bfr[ni][ks], acc[mi][ni], 0, 0, 0);
    __syncthreads();
  }
#pragma unroll
  for (int ni = 0; ni < 2; ++ni) {
    int col = n0 + wn * 32 + ni * 16 + l16;
    float bias = bproj[col];
#pragma unroll
    for (int mi = 0; mi < 4; ++mi) {
      int rowb = s0 + wm * 64 + mi * 16 + quad * 4;
#pragma unroll
      for (int r = 0; r < 4; ++r)
        out[(size_t)(rowb + r) * D_ + col] = acc[mi][ni][r] + bias;
    }
  }
}

extern "C" void kernel_launch(void* const* d_in, const int* in_sizes, int n_in,
                              void* d_out, int out_size, void* d_ws, size_t ws_size,
                              hipStream_t stream) {
  const float* x = (const float*)d_in[0];
  const float* Wk = (const float*)d_in[1];
  const float* Wv = (const float*)d_in[2];
  const float* Wproj = (const float*)d_in[3];
  const float* bproj = (const float*)d_in[4];
  float* out = (float*)d_out;

  // Workspace layout (~40.5 MB total)
  char* ws = (char*)d_ws;
  unsigned short* xb = (unsigned short*)ws;                  // 4M bf16 = 8 MB
  unsigned short* Wkvt = xb + (size_t)BS_ * D_;              // 2M bf16 = 4 MB
  unsigned short* Kb = Wkvt + (size_t)H_ * 128 * D_;         // 4M bf16 = 8 MB
  unsigned short* Vb = Kb + (size_t)BS_ * HD_;               // 4M bf16 = 8 MB
  float* Mpart = (float*)(Vb + (size_t)BS_ * HD_);           // 2M f32 = 8 MB
  float* M = Mpart + (size_t)SPLIT * B_ * H_ * HS_ * HS_;    // 128K f32 = 0.5 MB
  unsigned short* Pt = (unsigned short*)(M + (size_t)B_ * H_ * HS_ * HS_);  // 2M bf16 = 4 MB

  prep_kernel<<<dim3(4096 + H_ * (D_ / 64)), dim3(256), 0, stream>>>(x, Wk, Wv, xb, Wkvt);
  kv_mfma_kernel<<<dim3((BS_ / 128) * H_), dim3(256), 0, stream>>>(xb, Wkvt, Kb, Vb);
  m_partial_kernel<<<dim3(SPLIT * B_ * H_), dim3(256), 0, stream>>>(Kb, Vb, Mpart);
  m_reduce_kernel<<<dim3(128), dim3(256), 0, stream>>>(Mpart, M);
  p_kernel<<<dim3(B_ * H_ * (D_ / 64)), dim3(256), 0, stream>>>(M, Wproj, Pt);
  out_mfma_kernel<<<dim3((BS_ / 128) * (D_ / 64)), dim3(256), 0, stream>>>(Vb, Pt, bproj, out);
}

// Round 5
// 139.491 us; speedup vs baseline: 3.3819x; 1.0404x over previous
//
#include <hip/hip_runtime.h>

// Shapes (fixed by the problem)
#define B_ 2
#define S_ 2048
#define D_ 1024
#define H_ 16
#define HS_ 64
#define HD_ 1024     // H_*HS_
#define SPLIT 16     // S-split for the K^T V reduction
#define BS_ (B_*S_)  // 4096 flattened rows
#define BK_ 64       // K-tile depth for kv_mfma
#define BKO_ 128     // K-tile depth for out_mfma

typedef __attribute__((ext_vector_type(8))) short short8_t;            // 8 bf16 (MFMA A/B frag)
typedef __attribute__((ext_vector_type(4))) float float4_t;            // MFMA C/D frag

__device__ inline unsigned short f32_to_bf16(float f) {
  unsigned int u = __float_as_uint(f);
  u += 0x7FFF + ((u >> 16) & 1);   // round-to-nearest-even
  return (unsigned short)(u >> 16);
}

// async global->LDS, 16B per lane. LDS dest is wave-uniform base + lane*16.
__device__ inline void async_copy16(const void* g, void* lds) {
  __builtin_amdgcn_global_load_lds(
      (const __attribute__((address_space(1))) void*)g,
      (__attribute__((address_space(3))) void*)lds, 16, 0, 0);
}

// XOR swizzle: LDS[row][phys chunk c] holds global chunk c ^ (row&7).
// Frag read of logical chunk q from row R -> phys q ^ (R&7); across a 16-lane
// group R&7 sweeps 8 values -> 32 banks covered, 2 lanes/bank = free (m136).

// ---------------------------------------------------------------------------
// prep: blocks [0,4096) convert x fp32->bf16 (4 elems/thread);
// blocks [4096,4352) build Wkvt[h][128][d] bf16 (rows 0-63 = Wk cols,
// rows 64-127 = Wv cols), k(d)-contiguous for kv_mfma B staging.
// ---------------------------------------------------------------------------
__global__ __launch_bounds__(256) void prep_kernel(
    const float* __restrict__ x, const float* __restrict__ Wk,
    const float* __restrict__ Wv, unsigned short* __restrict__ xb,
    unsigned short* __restrict__ Wkvt) {
  const int blk = blockIdx.x;
  const int tid = threadIdx.x;
  __shared__ float lds[64][65];
  if (blk < 4096) {
    int idx = blk * 256 + tid;
    float4 v = ((const float4*)x)[idx];
    ushort4 o;
    o.x = f32_to_bf16(v.x); o.y = f32_to_bf16(v.y);
    o.z = f32_to_bf16(v.z); o.w = f32_to_bf16(v.w);
    ((ushort4*)xb)[idx] = o;
    return;
  }
  const int wblk = blk - 4096;
  const int h = wblk >> 4;
  const int d0 = (wblk & 15) * 64;
  // K half
#pragma unroll
  for (int i = 0; i < 16; ++i) {
    int idx = tid + i * 256; int dd = idx >> 6, e = idx & 63;
    lds[e][dd] = Wk[((size_t)h * D_ + d0 + dd) * HS_ + e];
  }
  __syncthreads();
#pragma unroll
  for (int i = 0; i < 16; ++i) {
    int idx = tid + i * 256; int e = idx >> 6, dd = idx & 63;
    Wkvt[((size_t)h * 128 + e) * D_ + d0 + dd] = f32_to_bf16(lds[e][dd]);
  }
  __syncthreads();
  // V half
#pragma unroll
  for (int i = 0; i < 16; ++i) {
    int idx = tid + i * 256; int dd = idx >> 6, e = idx & 63;
    lds[e][dd] = Wv[((size_t)h * D_ + d0 + dd) * HS_ + e];
  }
  __syncthreads();
#pragma unroll
  for (int i = 0; i < 16; ++i) {
    int idx = tid + i * 256; int e = idx >> 6, dd = idx & 63;
    Wkvt[((size_t)h * 128 + 64 + e) * D_ + d0 + dd] = f32_to_bf16(lds[e][dd]);
  }
}

// ---------------------------------------------------------------------------
// kv_mfma: 128(s) x 64(one head's K or V) tiles -> grid 32*32 = 1024 blocks
// (4 blocks/CU), BK=64, swizzled LDS. 4 waves stacked in m (each 32x64).
// half==0 tiles write Kt[f][s] only; half==1 write Vb[s][hd] + Vt[e][s].
// ---------------------------------------------------------------------------
__global__ __launch_bounds__(256, 4) void kv_mfma_kernel(
    const unsigned short* __restrict__ xb,    // [4096][1024]
    const unsigned short* __restrict__ Wkvt,  // [16][128][1024]
    unsigned short* __restrict__ Kt,          // [1024][4096]
    unsigned short* __restrict__ Vb,          // [4096][1024]
    unsigned short* __restrict__ Vt) {        // [1024][4096]
  const int blk = blockIdx.x;
  const int stile = blk & 31;
  const int ntile = blk >> 5;                // 32 tiles of 64 cols
  const int h = ntile >> 1, half = ntile & 1;
  const int s0 = stile * 128;
  const int tid = threadIdx.x;
  const int lane = tid & 63;
  const int wid = tid >> 6;
  const int quad = lane >> 4, l16 = lane & 15;
  const int srow8 = lane >> 3;
  const int csw = ((lane & 7) ^ srow8) * 8;
  const int xa = l16 & 7;

  __shared__ __align__(16) unsigned short As[128 * BK_];  // 16 KB
  __shared__ __align__(16) unsigned short Bs[64 * BK_];   //  8 KB

  float4_t acc[2][4];                        // wave tile 32(m) x 64(n)
  const float4_t fz = {0.f, 0.f, 0.f, 0.f};
#pragma unroll
  for (int i = 0; i < 2; ++i)
#pragma unroll
    for (int j = 0; j < 4; ++j) acc[i][j] = fz;

  const unsigned short* Brow = Wkvt + ((size_t)h * 128 + half * 64) * D_;
  for (int k0 = 0; k0 < D_; k0 += BK_) {
#pragma unroll
    for (int i = 0; i < 4; ++i) {            // A: 16 row-groups of 8
      int g = wid * 4 + i;
      int r = g * 8 + srow8;
      async_copy16(xb + (size_t)(s0 + r) * D_ + k0 + csw, As + g * 8 * BK_);
    }
#pragma unroll
    for (int i = 0; i < 2; ++i) {            // B: 8 row-groups of 8
      int g = wid * 2 + i;
      int r = g * 8 + srow8;
      async_copy16(Brow + (size_t)r * D_ + k0 + csw, Bs + g * 8 * BK_);
    }
    __syncthreads();
    short8_t a[2][2], b[4][2];
#pragma unroll
    for (int mi = 0; mi < 2; ++mi)
#pragma unroll
      for (int ks = 0; ks < 2; ++ks)
        a[mi][ks] = *(const short8_t*)(As + (wid * 32 + mi * 16 + l16) * BK_ +
                                       ((ks * 4 + quad) ^ xa) * 8);
#pragma unroll
    for (int ni = 0; ni < 4; ++ni)
#pragma unroll
      for (int ks = 0; ks < 2; ++ks)
        b[ni][ks] = *(const short8_t*)(Bs + (ni * 16 + l16) * BK_ +
                                       ((ks * 4 + quad) ^ xa) * 8);
#pragma unroll
    for (int ks = 0; ks < 2; ++ks)
#pragma unroll
      for (int mi = 0; mi < 2; ++mi)
#pragma unroll
        for (int ni = 0; ni < 4; ++ni)
          acc[mi][ni] = __builtin_amdgcn_mfma_f32_16x16x32_bf16(
              a[mi][ks], b[ni][ks], acc[mi][ni], 0, 0, 0);
    __syncthreads();
  }
  // Epilogue. C/D layout: col(n)=l16, row(m)=quad*4+r (4 consecutive s).
#pragma unroll
  for (int mi = 0; mi < 2; ++mi)
#pragma unroll
    for (int ni = 0; ni < 4; ++ni) {
      int fr = h * 64 + ni * 16 + l16;                 // feature row
      int sc = s0 + wid * 32 + mi * 16 + quad * 4;     // s col (4 consecutive)
      ushort4 o;
      o.x = f32_to_bf16(acc[mi][ni][0]);
      o.y = f32_to_bf16(acc[mi][ni][1]);
      o.z = f32_to_bf16(acc[mi][ni][2]);
      o.w = f32_to_bf16(acc[mi][ni][3]);
      if (half == 0) {
        *(ushort4*)&Kt[(size_t)fr * BS_ + sc] = o;
      } else {
        *(ushort4*)&Vt[(size_t)fr * BS_ + sc] = o;
#pragma unroll
        for (int r = 0; r < 4; ++r)
          Vb[(size_t)(sc + r) * HD_ + fr] = ((const unsigned short*)&o)[r];
      }
    }
}

// ---------------------------------------------------------------------------
// m_partial: one 64-lane wave per (split,b,h). Zero LDS — A/B frags are
// direct 16B global loads from Kt/Vt (s-contiguous rows). K-slice = 128.
// Mpart[split][b][h][f][e] fp32. grid = 512 blocks x 64 threads.
// ---------------------------------------------------------------------------
__global__ __launch_bounds__(64) void m_partial_kernel(
    const unsigned short* __restrict__ Kt, const unsigned short* __restrict__ Vt,
    float* __restrict__ Mpart) {
  const int blk = blockIdx.x;
  const int h = blk & 15;
  const int b = (blk >> 4) & 1;
  const int split = blk >> 5;
  const int lane = threadIdx.x;
  const int quad = lane >> 4, l16 = lane & 15;
  const int sBase = b * S_ + split * (S_ / SPLIT);

  const unsigned short* Krow = Kt + (size_t)h * 64 * BS_;
  const unsigned short* Vrow = Vt + (size_t)h * 64 * BS_;

  float4_t acc[4][4];
  const float4_t fz = {0.f, 0.f, 0.f, 0.f};
#pragma unroll
  for (int i = 0; i < 4; ++i)
#pragma unroll
    for (int j = 0; j < 4; ++j) acc[i][j] = fz;

  for (int sc = 0; sc < S_ / SPLIT; sc += 32) {
    short8_t a[4], bfr[4];
#pragma unroll
    for (int mi = 0; mi < 4; ++mi)
      a[mi] = *(const short8_t*)&Krow[(size_t)(mi * 16 + l16) * BS_ + sBase + sc + quad * 8];
#pragma unroll
    for (int ni = 0; ni < 4; ++ni)
      bfr[ni] = *(const short8_t*)&Vrow[(size_t)(ni * 16 + l16) * BS_ + sBase + sc + quad * 8];
#pragma unroll
    for (int mi = 0; mi < 4; ++mi)
#pragma unroll
      for (int ni = 0; ni < 4; ++ni)
        acc[mi][ni] = __builtin_amdgcn_mfma_f32_16x16x32_bf16(
            a[mi], bfr[ni], acc[mi][ni], 0, 0, 0);
  }
  float* dst = Mpart + (((size_t)split * B_ + b) * H_ + h) * 4096;
#pragma unroll
  for (int mi = 0; mi < 4; ++mi)
#pragma unroll
    for (int ni = 0; ni < 4; ++ni)
#pragma unroll
      for (int r = 0; r < 4; ++r)
        dst[(mi * 16 + quad * 4 + r) * 64 + ni * 16 + l16] = acc[mi][ni][r];
}

// ---------------------------------------------------------------------------
// m_reduce: sum SPLIT partials, apply 0.125 scale. grid = 128 blocks.
// ---------------------------------------------------------------------------
__global__ __launch_bounds__(256) void m_reduce_kernel(
    const float* __restrict__ Mpart, float* __restrict__ M) {
  const int gid = blockIdx.x * 256 + threadIdx.x;
  const int e0 = gid * 4;               // [0, 131072)
  const int bh = e0 >> 12;
  const int idx = e0 & 4095;
  float4 s = {0.f, 0.f, 0.f, 0.f};
#pragma unroll
  for (int p = 0; p < SPLIT; ++p) {
    const float4 v = *(const float4*)&Mpart[((size_t)(p * B_ * H_) + bh) * 4096 + idx];
    s.x += v.x; s.y += v.y; s.z += v.z; s.w += v.w;
  }
  s.x *= 0.125f; s.y *= 0.125f; s.z *= 0.125f; s.w *= 0.125f;
  *(float4*)&M[(size_t)bh * 4096 + idx] = s;
}

// ---------------------------------------------------------------------------
// p_kernel: P[b][h*64+f][d] = sum_e M[b,h,f,e]*Wproj[h*64+e][d], written
// TRANSPOSED as Pt[b][d][h*64+f] bf16 (k-contiguous for out_mfma staging).
// grid = B*H*(D/64) = 512 blocks.
// ---------------------------------------------------------------------------
__global__ __launch_bounds__(256) void p_kernel(
    const float* __restrict__ M, const float* __restrict__ Wproj,
    unsigned short* __restrict__ Pt) {
  const int blk = blockIdx.x;
  const int dtile = blk & 15;
  const int h = (blk >> 4) & 15;
  const int b = blk >> 8;
  const int d0 = dtile * 64;
  const int tid = threadIdx.x;
  const int tx = tid & 15, ty = tid >> 4;
  __shared__ float Ms[64][68];  // A: [e][f] (transposed on store)
  __shared__ float Ws[64][68];  // B: [e][d]
  const size_t mbase = ((size_t)(b * H_ + h)) * HS_ * HS_;
#pragma unroll
  for (int i = 0; i < 16; ++i) {
    int idx = tid + i * 256;
    int f = idx >> 6, e = idx & 63;
    Ms[e][f] = M[mbase + idx];
    Ws[f][e] = Wproj[(size_t)(h * HS_ + f) * D_ + d0 + e];
  }
  __syncthreads();
  float acc[4][4] = {};
#pragma unroll
  for (int kk = 0; kk < 64; ++kk) {
    const float4 a4 = *(const float4*)&Ms[kk][ty * 4];
    const float4 b4 = *(const float4*)&Ws[kk][tx * 4];
    const float a[4] = {a4.x, a4.y, a4.z, a4.w};
    const float bb[4] = {b4.x, b4.y, b4.z, b4.w};
#pragma unroll
    for (int i = 0; i < 4; ++i)
#pragma unroll
      for (int j = 0; j < 4; ++j) acc[i][j] += a[i] * bb[j];
  }
  // transpose through LDS: trans[d][f] then linear bf16 rows
  __syncthreads();
#pragma unroll
  for (int i = 0; i < 4; ++i)
#pragma unroll
    for (int j = 0; j < 4; ++j)
      Ms[tx * 4 + j][ty * 4 + i] = acc[i][j];
  __syncthreads();
  {
    int c = tid >> 2, ch = tid & 3;  // row c (d-dim), 16-elem chunk of f-dim
    unsigned short* dst = Pt + ((size_t)(b * D_ + d0 + c)) * HD_ + h * 64 + ch * 16;
#pragma unroll
    for (int e = 0; e < 16; ++e) dst[e] = f32_to_bf16(Ms[c][ch * 16 + e]);
  }
}

// ---------------------------------------------------------------------------
// out_mfma: out[s][d] = bproj[d] + sum_j Vb[s][j]*Pt[b][d][j].
// 128x64 tiles, grid 512 (2/CU), BK=128 (8 iters), swizzled LDS.
// 4 waves as 2(m)x2(n), each wave 64x32.
// ---------------------------------------------------------------------------
__global__ __launch_bounds__(256) void out_mfma_kernel(
    const unsigned short* __restrict__ Vb,   // [4096][1024]
    const unsigned short* __restrict__ Pt,   // [2][1024][1024]
    const float* __restrict__ bproj,
    float* __restrict__ out) {
  const int blk = blockIdx.x;
  const int ntile = blk & 15;              // 1024/64 = 16
  const int stile = blk >> 4;              // 4096/128 = 32
  const int s0 = stile * 128;
  const int n0 = ntile * 64;
  const int b = s0 >> 11;
  const int tid = threadIdx.x;
  const int lane = tid & 63;
  const int wid = tid >> 6;
  const int wm = wid & 1, wn = wid >> 1;
  const int quad = lane >> 4, l16 = lane & 15;
  const int srow4 = lane >> 4;             // 4 rows per copy instr (256B rows)
  const int xa = l16 & 7;

  __shared__ __align__(16) unsigned short As[128 * BKO_];  // 32 KB
  __shared__ __align__(16) unsigned short Bs[64 * BKO_];   // 16 KB

  float4_t acc[4][2];
  const float4_t fz = {0.f, 0.f, 0.f, 0.f};
#pragma unroll
  for (int i = 0; i < 4; ++i)
#pragma unroll
    for (int j = 0; j < 2; ++j) acc[i][j] = fz;

  const unsigned short* Bpanel = Pt + (size_t)b * D_ * HD_;
  for (int k0 = 0; k0 < HD_; k0 += BKO_) {
#pragma unroll
    for (int i = 0; i < 8; ++i) {        // A: 32 groups of 4 rows
      int g = wid * 8 + i;
      int r = g * 4 + srow4;
      int ch = (l16 ^ (r & 7)) * 8;      // swizzled 16B chunk (elems)
      async_copy16(Vb + (size_t)(s0 + r) * HD_ + k0 + ch, As + g * 4 * BKO_);
    }
#pragma unroll
    for (int i = 0; i < 4; ++i) {        // B: 16 groups of 4 rows
      int g = wid * 4 + i;
      int r = g * 4 + srow4;
      int ch = (l16 ^ (r & 7)) * 8;
      async_copy16(Bpanel + (size_t)(n0 + r) * HD_ + k0 + ch, Bs + g * 4 * BKO_);
    }
    __syncthreads();
    short8_t a[4][4], bfr[2][4];
#pragma unroll
    for (int mi = 0; mi < 4; ++mi)
#pragma unroll
      for (int ks = 0; ks < 4; ++ks)
        a[mi][ks] = *(const short8_t*)(As + (wm * 64 + mi * 16 + l16) * BKO_ +
                                       ((ks * 4 + quad) ^ xa) * 8);
#pragma unroll
    for (int ni = 0; ni < 2; ++ni)
#pragma unroll
      for (int ks = 0; ks < 4; ++ks)
        bfr[ni][ks] = *(const short8_t*)(Bs + (wn * 32 + ni * 16 + l16) * BKO_ +
                                         ((ks * 4 + quad) ^ xa) * 8);
#pragma unroll
    for (int ks = 0; ks < 4; ++ks)
#pragma unroll
      for (int mi = 0; mi < 4; ++mi)
#pragma unroll
        for (int ni = 0; ni < 2; ++ni)
          acc[mi][ni] = __builtin_amdgcn_mfma_f32_16x16x32_bf16(
              a[mi][ks], bfr[ni][ks], acc[mi][ni], 0, 0, 0);
    __syncthreads();
  }
#pragma unroll
  for (int ni = 0; ni < 2; ++ni) {
    int col = n0 + wn * 32 + ni * 16 + l16;
    float bias = bproj[col];
#pragma unroll
    for (int mi = 0; mi < 4; ++mi) {
      int rowb = s0 + wm * 64 + mi * 16 + quad * 4;
#pragma unroll
      for (int r = 0; r < 4; ++r)
        out[(size_t)(rowb + r) * D_ + col] = acc[mi][ni][r] + bias;
    }
  }
}

extern "C" void kernel_launch(void* const* d_in, const int* in_sizes, int n_in,
                              void* d_out, int out_size, void* d_ws, size_t ws_size,
                              hipStream_t stream) {
  const float* x = (const float*)d_in[0];
  const float* Wk = (const float*)d_in[1];
  const float* Wv = (const float*)d_in[2];
  const float* Wproj = (const float*)d_in[3];
  const float* bproj = (const float*)d_in[4];
  float* out = (float*)d_out;

  // Workspace layout (~48.5 MB total)
  char* ws = (char*)d_ws;
  unsigned short* xb = (unsigned short*)ws;                  // 4M bf16 = 8 MB
  unsigned short* Wkvt = xb + (size_t)BS_ * D_;              // 2M bf16 = 4 MB
  unsigned short* Kt = Wkvt + (size_t)H_ * 128 * D_;         // 4M bf16 = 8 MB  [1024][4096]
  unsigned short* Vb = Kt + (size_t)HD_ * BS_;               // 4M bf16 = 8 MB  [4096][1024]
  unsigned short* Vt = Vb + (size_t)BS_ * HD_;               // 4M bf16 = 8 MB  [1024][4096]
  float* Mpart = (float*)(Vt + (size_t)HD_ * BS_);           // 2M f32 = 8 MB
  float* M = Mpart + (size_t)SPLIT * B_ * H_ * HS_ * HS_;    // 128K f32 = 0.5 MB
  unsigned short* Pt = (unsigned short*)(M + (size_t)B_ * H_ * HS_ * HS_);  // 2M bf16 = 4 MB

  prep_kernel<<<dim3(4096 + H_ * (D_ / 64)), dim3(256), 0, stream>>>(x, Wk, Wv, xb, Wkvt);
  kv_mfma_kernel<<<dim3(32 * 32), dim3(256), 0, stream>>>(xb, Wkvt, Kt, Vb, Vt);
  m_partial_kernel<<<dim3(SPLIT * B_ * H_), dim3(64), 0, stream>>>(Kt, Vt, Mpart);
  m_reduce_kernel<<<dim3(128), dim3(256), 0, stream>>>(Mpart, M);
  p_kernel<<<dim3(B_ * H_ * (D_ / 64)), dim3(256), 0, stream>>>(M, Wproj, Pt);
  out_mfma_kernel<<<dim3(32 * 16), dim3(256), 0, stream>>>(Vb, Pt, bproj, out);
}

// Round 6
// 133.562 us; speedup vs baseline: 3.5320x; 1.0444x over previous
//
#include <hip/hip_runtime.h>

// Shapes (fixed by the problem)
#define B_ 2
#define S_ 2048
#define D_ 1024
#define H_ 16
#define HS_ 64
#define HD_ 1024     // H_*HS_
#define BS_ (B_*S_)  // 4096 flattened rows
#define BK_ 64       // K-tile depth for kv_mfma
#define BKO_ 128     // K-tile depth for out_mfma
#define TP_ 136      // padded row length (elems) for transposed LDS tiles

typedef __attribute__((ext_vector_type(8))) short short8_t;   // 8 bf16 (MFMA A/B frag)
typedef __attribute__((ext_vector_type(4))) float float4_t;   // MFMA C/D frag

__device__ inline unsigned short f32_to_bf16(float f) {
  unsigned int u = __float_as_uint(f);
  u += 0x7FFF + ((u >> 16) & 1);   // round-to-nearest-even
  return (unsigned short)(u >> 16);
}

// async global->LDS, 16B per lane. LDS dest is wave-uniform base + lane*16.
__device__ inline void async_copy16(const void* g, void* lds) {
  __builtin_amdgcn_global_load_lds(
      (const __attribute__((address_space(1))) void*)g,
      (__attribute__((address_space(3))) void*)lds, 16, 0, 0);
}

// XOR swizzle: LDS[row][phys chunk c] holds global chunk c ^ (row&7).
// Frag read of logical chunk q from row R -> phys q ^ (R&7); across a 16-lane
// group R&7 sweeps 8 values -> 32 banks covered, 2 lanes/bank = free (m136).

// ---------------------------------------------------------------------------
// prep: blocks [0,4096) convert x fp32->bf16 (4 elems/thread);
// blocks [4096,4352) build Wkvt[h][128][d] bf16 (rows 0-63 = Wk cols,
// rows 64-127 = Wv cols), k(d)-contiguous for kv_mfma B staging.
// ---------------------------------------------------------------------------
__global__ __launch_bounds__(256) void prep_kernel(
    const float* __restrict__ x, const float* __restrict__ Wk,
    const float* __restrict__ Wv, unsigned short* __restrict__ xb,
    unsigned short* __restrict__ Wkvt) {
  const int blk = blockIdx.x;
  const int tid = threadIdx.x;
  __shared__ float lds[64][65];
  if (blk < 4096) {
    int idx = blk * 256 + tid;
    float4 v = ((const float4*)x)[idx];
    ushort4 o;
    o.x = f32_to_bf16(v.x); o.y = f32_to_bf16(v.y);
    o.z = f32_to_bf16(v.z); o.w = f32_to_bf16(v.w);
    ((ushort4*)xb)[idx] = o;
    return;
  }
  const int wblk = blk - 4096;
  const int h = wblk >> 4;
  const int d0 = (wblk & 15) * 64;
  // K half
#pragma unroll
  for (int i = 0; i < 16; ++i) {
    int idx = tid + i * 256; int dd = idx >> 6, e = idx & 63;
    lds[e][dd] = Wk[((size_t)h * D_ + d0 + dd) * HS_ + e];
  }
  __syncthreads();
#pragma unroll
  for (int i = 0; i < 16; ++i) {
    int idx = tid + i * 256; int e = idx >> 6, dd = idx & 63;
    Wkvt[((size_t)h * 128 + e) * D_ + d0 + dd] = f32_to_bf16(lds[e][dd]);
  }
  __syncthreads();
  // V half
#pragma unroll
  for (int i = 0; i < 16; ++i) {
    int idx = tid + i * 256; int dd = idx >> 6, e = idx & 63;
    lds[e][dd] = Wv[((size_t)h * D_ + d0 + dd) * HS_ + e];
  }
  __syncthreads();
#pragma unroll
  for (int i = 0; i < 16; ++i) {
    int idx = tid + i * 256; int e = idx >> 6, dd = idx & 63;
    Wkvt[((size_t)h * 128 + 64 + e) * D_ + d0 + dd] = f32_to_bf16(lds[e][dd]);
  }
}

// ---------------------------------------------------------------------------
// kv_mfma (fused): per (stile,h):
//   phase 1: [128 s x 128 (64 K | 64 V)] = x-tile @ Wkvt_h   (m97 structure)
//   phase 2: LDS-transpose K,V -> Mpart[stile][h] = K^T V via MFMA (K never
//            touches global memory); V written to Vb for out_mfma.
// grid = 32*16 = 512 blocks, 256 threads (4 waves as 2x2 of 64x64).
// ---------------------------------------------------------------------------
__global__ __launch_bounds__(256) void kv_mfma_kernel(
    const unsigned short* __restrict__ xb,    // [4096][1024]
    const unsigned short* __restrict__ Wkvt,  // [16][128][1024]
    unsigned short* __restrict__ Vb,          // [4096][1024]
    float* __restrict__ Mpart) {              // [32][16][64][64]
  const int blk = blockIdx.x;
  const int stile = blk & 31;
  const int h = blk >> 5;
  const int s0 = stile * 128;
  const int tid = threadIdx.x;
  const int lane = tid & 63;
  const int wid = tid >> 6;
  const int wm = wid & 1, wn = wid >> 1;
  const int quad = lane >> 4, l16 = lane & 15;
  const int srow8 = lane >> 3;
  const int csw = ((lane & 7) ^ srow8) * 8;
  const int xa = l16 & 7;

  // Aliased LDS: phase 1 uses As/Bs (32 KB); phase 2 reuses it as Ktl/Vtl
  // transposed tiles [64][TP_] (34 KB total).
  __shared__ __align__(16) unsigned char smem[2 * 64 * TP_ * 2];
  unsigned short* As  = (unsigned short*)smem;                    // [128][64]
  unsigned short* Bs  = (unsigned short*)(smem + 128 * BK_ * 2);  // [128][64]
  unsigned short* Ktl = (unsigned short*)smem;                    // [64][TP_]
  unsigned short* Vtl = (unsigned short*)(smem + 64 * TP_ * 2);   // [64][TP_]

  float4_t acc[4][4];
  const float4_t fz = {0.f, 0.f, 0.f, 0.f};
#pragma unroll
  for (int i = 0; i < 4; ++i)
#pragma unroll
    for (int j = 0; j < 4; ++j) acc[i][j] = fz;

  for (int k0 = 0; k0 < D_; k0 += BK_) {
#pragma unroll
    for (int i = 0; i < 4; ++i) {      // 16 row-groups of 8 for A and B each
      int g = wid * 4 + i;
      int r = g * 8 + srow8;
      async_copy16(xb + (size_t)(s0 + r) * D_ + k0 + csw, As + g * 8 * BK_);
      async_copy16(Wkvt + ((size_t)h * 128 + r) * D_ + k0 + csw, Bs + g * 8 * BK_);
    }
    __syncthreads();
    short8_t a[4][2], b[4][2];
#pragma unroll
    for (int mi = 0; mi < 4; ++mi)
#pragma unroll
      for (int ks = 0; ks < 2; ++ks)
        a[mi][ks] = *(const short8_t*)(As + (wm * 64 + mi * 16 + l16) * BK_ +
                                       ((ks * 4 + quad) ^ xa) * 8);
#pragma unroll
    for (int ni = 0; ni < 4; ++ni)
#pragma unroll
      for (int ks = 0; ks < 2; ++ks)
        b[ni][ks] = *(const short8_t*)(Bs + (wn * 64 + ni * 16 + l16) * BK_ +
                                       ((ks * 4 + quad) ^ xa) * 8);
#pragma unroll
    for (int ks = 0; ks < 2; ++ks)
#pragma unroll
      for (int mi = 0; mi < 4; ++mi)
#pragma unroll
        for (int ni = 0; ni < 4; ++ni)
          acc[mi][ni] = __builtin_amdgcn_mfma_f32_16x16x32_bf16(
              a[mi][ks], b[ni][ks], acc[mi][ni], 0, 0, 0);
    __syncthreads();
  }

  // ---- phase 2a: dump quadrants transposed into LDS (bf16) ----
  // C/D layout: col = wn*64 + ni*16 + l16 (0-63 = K feat, 64-127 = V feat),
  // rows = wm*64 + mi*16 + quad*4 + r (4 consecutive s).
  {
    unsigned short* dstT = (wn == 0) ? Ktl : Vtl;
#pragma unroll
    for (int mi = 0; mi < 4; ++mi)
#pragma unroll
      for (int ni = 0; ni < 4; ++ni) {
        int f = ni * 16 + l16;
        int sm = wm * 64 + mi * 16 + quad * 4;
        ushort4 o;
        o.x = f32_to_bf16(acc[mi][ni][0]);
        o.y = f32_to_bf16(acc[mi][ni][1]);
        o.z = f32_to_bf16(acc[mi][ni][2]);
        o.w = f32_to_bf16(acc[mi][ni][3]);
        *(ushort4*)&dstT[f * TP_ + sm] = o;
      }
  }
  __syncthreads();

  // ---- phase 2b: Vb[s0+s][h*64+e] from Vtl (16B stores, conflict-free LDS) ----
#pragma unroll
  for (int u = 0; u < 4; ++u) {
    int unit = tid + u * 256;            // 0..1023 = 128 s x 8 e-chunks
    int s = unit & 127;                  // lanes consecutive in s -> LDS reads
    int ec = (unit >> 7) * 8;            // spread across banks (2/bank)
    union { unsigned short u16[8]; uint4 v; } t;
#pragma unroll
    for (int e = 0; e < 8; ++e) t.u16[e] = Vtl[(ec + e) * TP_ + s];
    *(uint4*)&Vb[(size_t)(s0 + s) * HD_ + h * 64 + ec] = t.v;
  }

  // ---- phase 2c: Mpart[f][e] = sum_{s<128} K[s,f] V[s,e] via MFMA ----
  // wave w computes f in [w*16, w*16+16); A = Ktl rows, B = Vtl rows.
  {
    float4_t macc[4];
#pragma unroll
    for (int ni = 0; ni < 4; ++ni) macc[ni] = fz;
#pragma unroll
    for (int ss = 0; ss < 4; ++ss) {     // 4 k-steps of 32 s
      short8_t ka = *(const short8_t*)&Ktl[(wid * 16 + l16) * TP_ + ss * 32 + quad * 8];
#pragma unroll
      for (int ni = 0; ni < 4; ++ni) {
        short8_t vv = *(const short8_t*)&Vtl[(ni * 16 + l16) * TP_ + ss * 32 + quad * 8];
        macc[ni] = __builtin_amdgcn_mfma_f32_16x16x32_bf16(ka, vv, macc[ni], 0, 0, 0);
      }
    }
    float* mdst = Mpart + ((size_t)stile * H_ + h) * 4096;
#pragma unroll
    for (int ni = 0; ni < 4; ++ni) {
      int e = ni * 16 + l16;
#pragma unroll
      for (int r = 0; r < 4; ++r) {
        int f = wid * 16 + quad * 4 + r;
        mdst[f * 64 + e] = macc[ni][r];
      }
    }
  }
}

// ---------------------------------------------------------------------------
// m_reduce: M[b,h] = 0.125 * sum over the 16 stiles of batch b. 128 blocks.
// ---------------------------------------------------------------------------
__global__ __launch_bounds__(256) void m_reduce_kernel(
    const float* __restrict__ Mpart, float* __restrict__ M) {
  const int gid = blockIdx.x * 256 + threadIdx.x;
  const int e0 = gid * 4;               // [0, 131072)
  const int bh = e0 >> 12;              // b*16+h
  const int idx = e0 & 4095;
  const int b = bh >> 4, h = bh & 15;
  float4 s = {0.f, 0.f, 0.f, 0.f};
#pragma unroll
  for (int p = 0; p < 16; ++p) {
    const float4 v =
        *(const float4*)&Mpart[(((size_t)(b * 16 + p)) * H_ + h) * 4096 + idx];
    s.x += v.x; s.y += v.y; s.z += v.z; s.w += v.w;
  }
  s.x *= 0.125f; s.y *= 0.125f; s.z *= 0.125f; s.w *= 0.125f;
  *(float4*)&M[(size_t)bh * 4096 + idx] = s;
}

// ---------------------------------------------------------------------------
// p_kernel: P[b][h*64+f][d] = sum_e M[b,h,f,e]*Wproj[h*64+e][d], written
// TRANSPOSED as Pt[b][d][h*64+f] bf16 (k-contiguous for out_mfma staging).
// grid = B*H*(D/64) = 512 blocks.
// ---------------------------------------------------------------------------
__global__ __launch_bounds__(256) void p_kernel(
    const float* __restrict__ M, const float* __restrict__ Wproj,
    unsigned short* __restrict__ Pt) {
  const int blk = blockIdx.x;
  const int dtile = blk & 15;
  const int h = (blk >> 4) & 15;
  const int b = blk >> 8;
  const int d0 = dtile * 64;
  const int tid = threadIdx.x;
  const int tx = tid & 15, ty = tid >> 4;
  __shared__ float Ms[64][68];  // A: [e][f] (transposed on store)
  __shared__ float Ws[64][68];  // B: [e][d]
  const size_t mbase = ((size_t)(b * H_ + h)) * HS_ * HS_;
#pragma unroll
  for (int i = 0; i < 16; ++i) {
    int idx = tid + i * 256;
    int f = idx >> 6, e = idx & 63;
    Ms[e][f] = M[mbase + idx];
    Ws[f][e] = Wproj[(size_t)(h * HS_ + f) * D_ + d0 + e];
  }
  __syncthreads();
  float acc[4][4] = {};
#pragma unroll
  for (int kk = 0; kk < 64; ++kk) {
    const float4 a4 = *(const float4*)&Ms[kk][ty * 4];
    const float4 b4 = *(const float4*)&Ws[kk][tx * 4];
    const float a[4] = {a4.x, a4.y, a4.z, a4.w};
    const float bb[4] = {b4.x, b4.y, b4.z, b4.w};
#pragma unroll
    for (int i = 0; i < 4; ++i)
#pragma unroll
      for (int j = 0; j < 4; ++j) acc[i][j] += a[i] * bb[j];
  }
  // transpose through LDS: trans[d][f] then linear bf16 rows
  __syncthreads();
#pragma unroll
  for (int i = 0; i < 4; ++i)
#pragma unroll
    for (int j = 0; j < 4; ++j)
      Ms[tx * 4 + j][ty * 4 + i] = acc[i][j];
  __syncthreads();
  {
    int c = tid >> 2, ch = tid & 3;  // row c (d-dim), 16-elem chunk of f-dim
    unsigned short* dst = Pt + ((size_t)(b * D_ + d0 + c)) * HD_ + h * 64 + ch * 16;
#pragma unroll
    for (int e = 0; e < 16; ++e) dst[e] = f32_to_bf16(Ms[c][ch * 16 + e]);
  }
}

// ---------------------------------------------------------------------------
// out_mfma: out[s][d] = bproj[d] + sum_j Vb[s][j]*Pt[b][d][j].
// 128x64 tiles, grid 512 (2/CU), BK=128 (8 iters), swizzled LDS.
// 4 waves as 2(m)x2(n), each wave 64x32.
// ---------------------------------------------------------------------------
__global__ __launch_bounds__(256) void out_mfma_kernel(
    const unsigned short* __restrict__ Vb,   // [4096][1024]
    const unsigned short* __restrict__ Pt,   // [2][1024][1024]
    const float* __restrict__ bproj,
    float* __restrict__ out) {
  const int blk = blockIdx.x;
  const int ntile = blk & 15;              // 1024/64 = 16
  const int stile = blk >> 4;              // 4096/128 = 32
  const int s0 = stile * 128;
  const int n0 = ntile * 64;
  const int b = s0 >> 11;
  const int tid = threadIdx.x;
  const int lane = tid & 63;
  const int wid = tid >> 6;
  const int wm = wid & 1, wn = wid >> 1;
  const int quad = lane >> 4, l16 = lane & 15;
  const int srow4 = lane >> 4;             // 4 rows per copy instr (256B rows)
  const int xa = l16 & 7;

  __shared__ __align__(16) unsigned short As[128 * BKO_];  // 32 KB
  __shared__ __align__(16) unsigned short Bs[64 * BKO_];   // 16 KB

  float4_t acc[4][2];
  const float4_t fz = {0.f, 0.f, 0.f, 0.f};
#pragma unroll
  for (int i = 0; i < 4; ++i)
#pragma unroll
    for (int j = 0; j < 2; ++j) acc[i][j] = fz;

  const unsigned short* Bpanel = Pt + (size_t)b * D_ * HD_;
  for (int k0 = 0; k0 < HD_; k0 += BKO_) {
#pragma unroll
    for (int i = 0; i < 8; ++i) {        // A: 32 groups of 4 rows
      int g = wid * 8 + i;
      int r = g * 4 + srow4;
      int ch = (l16 ^ (r & 7)) * 8;      // swizzled 16B chunk (elems)
      async_copy16(Vb + (size_t)(s0 + r) * HD_ + k0 + ch, As + g * 4 * BKO_);
    }
#pragma unroll
    for (int i = 0; i < 4; ++i) {        // B: 16 groups of 4 rows
      int g = wid * 4 + i;
      int r = g * 4 + srow4;
      int ch = (l16 ^ (r & 7)) * 8;
      async_copy16(Bpanel + (size_t)(n0 + r) * HD_ + k0 + ch, Bs + g * 4 * BKO_);
    }
    __syncthreads();
    short8_t a[4][4], bfr[2][4];
#pragma unroll
    for (int mi = 0; mi < 4; ++mi)
#pragma unroll
      for (int ks = 0; ks < 4; ++ks)
        a[mi][ks] = *(const short8_t*)(As + (wm * 64 + mi * 16 + l16) * BKO_ +
                                       ((ks * 4 + quad) ^ xa) * 8);
#pragma unroll
    for (int ni = 0; ni < 2; ++ni)
#pragma unroll
      for (int ks = 0; ks < 4; ++ks)
        bfr[ni][ks] = *(const short8_t*)(Bs + (wn * 32 + ni * 16 + l16) * BKO_ +
                                         ((ks * 4 + quad) ^ xa) * 8);
#pragma unroll
    for (int ks = 0; ks < 4; ++ks)
#pragma unroll
      for (int mi = 0; mi < 4; ++mi)
#pragma unroll
        for (int ni = 0; ni < 2; ++ni)
          acc[mi][ni] = __builtin_amdgcn_mfma_f32_16x16x32_bf16(
              a[mi][ks], bfr[ni][ks], acc[mi][ni], 0, 0, 0);
    __syncthreads();
  }
#pragma unroll
  for (int ni = 0; ni < 2; ++ni) {
    int col = n0 + wn * 32 + ni * 16 + l16;
    float bias = bproj[col];
#pragma unroll
    for (int mi = 0; mi < 4; ++mi) {
      int rowb = s0 + wm * 64 + mi * 16 + quad * 4;
#pragma unroll
      for (int r = 0; r < 4; ++r)
        out[(size_t)(rowb + r) * D_ + col] = acc[mi][ni][r] + bias;
    }
  }
}

extern "C" void kernel_launch(void* const* d_in, const int* in_sizes, int n_in,
                              void* d_out, int out_size, void* d_ws, size_t ws_size,
                              hipStream_t stream) {
  const float* x = (const float*)d_in[0];
  const float* Wk = (const float*)d_in[1];
  const float* Wv = (const float*)d_in[2];
  const float* Wproj = (const float*)d_in[3];
  const float* bproj = (const float*)d_in[4];
  float* out = (float*)d_out;

  // Workspace layout (~32.5 MB total); every element written before read.
  char* ws = (char*)d_ws;
  unsigned short* xb = (unsigned short*)ws;                  // 4M bf16 = 8 MB
  unsigned short* Wkvt = xb + (size_t)BS_ * D_;              // 2M bf16 = 4 MB
  unsigned short* Vb = Wkvt + (size_t)H_ * 128 * D_;         // 4M bf16 = 8 MB
  float* Mpart = (float*)(Vb + (size_t)BS_ * HD_);           // 2M f32 = 8 MB  [32][16][4096]
  float* M = Mpart + (size_t)32 * H_ * 4096;                 // 128K f32 = 0.5 MB
  unsigned short* Pt = (unsigned short*)(M + (size_t)B_ * H_ * 4096);  // 2M bf16 = 4 MB

  prep_kernel<<<dim3(4096 + H_ * (D_ / 64)), dim3(256), 0, stream>>>(x, Wk, Wv, xb, Wkvt);
  kv_mfma_kernel<<<dim3(32 * H_), dim3(256), 0, stream>>>(xb, Wkvt, Vb, Mpart);
  m_reduce_kernel<<<dim3(128), dim3(256), 0, stream>>>(Mpart, M);
  p_kernel<<<dim3(B_ * H_ * (D_ / 64)), dim3(256), 0, stream>>>(M, Wproj, Pt);
  out_mfma_kernel<<<dim3(32 * 16), dim3(256), 0, stream>>>(Vb, Pt, bproj, out);
}